// Round 2
// baseline (1460.248 us; speedup 1.0000x reference)
//
#include <hip/hip_runtime.h>
#include <hip/hip_fp16.h>
#include <hip/hip_cooperative_groups.h>
#include <math.h>

namespace cg = cooperative_groups;

constexpr int B_ = 64;
constexpr int N_ = 4096;
constexpr int D_ = 256;
constexpr int NCH = 64;            // fallback path: chunks per batch row
constexpr int NPB = N_ / NCH;      // 64 rows per block
constexpr int NPW = NPB / 4;       // 16 rows per wave
constexpr int NSTEP = NPW / 4;     // fallback: 4 steps of 4 rows
constexpr int CNR = 16;            // rows per block in cn_kernel

// nontemporal float4 load (ext_vector to satisfy the builtin's type rules)
typedef float f4v __attribute__((ext_vector_type(4)));
__device__ __forceinline__ float4 nt_load4(const float4* p) {
    f4v v = __builtin_nontemporal_load((const f4v*)p);
    return make_float4(v.x, v.y, v.z, v.w);
}

// unpack 8 halves (two float4-sized raw loads) into 4 float4
__device__ __forceinline__ void cvt_h8(const float4 r0, const float4 r1, float4 m[4]) {
    const __half2* h0 = (const __half2*)&r0;
    const float2 f0 = __half22float2(h0[0]);
    const float2 f1 = __half22float2(h0[1]);
    const float2 f2 = __half22float2(h0[2]);
    const float2 f3 = __half22float2(h0[3]);
    m[0] = make_float4(f0.x, f0.y, f1.x, f1.y);
    m[1] = make_float4(f2.x, f2.y, f3.x, f3.y);
    const __half2* h1 = (const __half2*)&r1;
    const float2 g0 = __half22float2(h1[0]);
    const float2 g1 = __half22float2(h1[1]);
    const float2 g2 = __half22float2(h1[2]);
    const float2 g3 = __half22float2(h1[3]);
    m[2] = make_float4(g0.x, g0.y, g1.x, g1.y);
    m[3] = make_float4(g2.x, g2.y, g3.x, g3.y);
}

// ---------------------------------------------------------------------------
// flag: is precision == I?  0 -> fast paths everywhere.
// ---------------------------------------------------------------------------
__global__ __launch_bounds__(256) void flag_kernel(const float* __restrict__ P,
                                                   int* __restrict__ flag) {
    __shared__ int sh[256];
    const int tid = threadIdx.x;
    int bad = 0;
    for (int i = tid; i < D_ * D_; i += 256) {
        const int r = i >> 8, c = i & 255;
        const float expect = (r == c) ? 1.0f : 0.0f;
        bad |= (P[i] != expect) ? 1 : 0;
    }
    sh[tid] = bad;
    __syncthreads();
    for (int s = 128; s > 0; s >>= 1) {
        if (tid < s) sh[tid] |= sh[tid + s];
        __syncthreads();
    }
    if (tid == 0) *flag = sh[0];
}

// ---------------------------------------------------------------------------
// Cn[row] = 0.5 * m_row^T P m_row  (iteration-invariant general-P correction).
// Only meaningful when flag != 0; early-exits otherwise. 16 rows per block.
// ---------------------------------------------------------------------------
__global__ __launch_bounds__(256) void cn_kernel(const float* __restrict__ means,
                                                 const float* __restrict__ P,
                                                 const int* __restrict__ flag,
                                                 float* __restrict__ Cn) {
    if (*flag == 0) return;
    const int row0 = blockIdx.x * CNR;
    const int d = threadIdx.x;
    __shared__ __align__(16) float msh[CNR][D_];
    __shared__ float red[CNR][4];
    #pragma unroll
    for (int i = 0; i < CNR; i++)
        msh[i][d] = means[(size_t)(row0 + i) * D_ + d];
    __syncthreads();
    float acc[CNR];
    #pragma unroll
    for (int r = 0; r < CNR; r++) acc[r] = 0.f;
    for (int e = 0; e < D_; e++) {
        const float pde = P[d * D_ + e];
        #pragma unroll
        for (int r = 0; r < CNR; r++) acc[r] = fmaf(pde, msh[r][e], acc[r]);
    }
    const int lane = d & 63, wv = d >> 6;
    #pragma unroll
    for (int r = 0; r < CNR; r++) {
        float pv = msh[r][d] * acc[r];
        for (int s = 1; s < 64; s <<= 1) pv += __shfl_xor(pv, s, 64);
        if (lane == 0) red[r][wv] = pv;
    }
    __syncthreads();
    if (d < CNR)
        Cn[row0 + d] = 0.5f * (red[d][0] + red[d][1] + red[d][2] + red[d][3]);
}

// ---------------------------------------------------------------------------
// Online-softmax building blocks for the persistent kernel (no LDS, no bar).
// Expect in scope: m[4], vr[4], runM, runS, tacc[4].
// ---------------------------------------------------------------------------
#define REDUCE16(P)                                                            \
    P += __shfl_xor(P, 1, 64);                                                 \
    P += __shfl_xor(P, 2, 64);                                                 \
    P += __shfl_xor(P, 4, 64);                                                 \
    P += __shfl_xor(P, 8, 64);

#define ONLINE_UPDATE(SEXPR)                                                   \
    {                                                                          \
        const float s_ = (SEXPR);                                              \
        const float newM_ = fmaxf(runM, s_);                                   \
        const float sc_ = __expf(runM - newM_);                                \
        const float e_  = __expf(s_ - newM_);                                  \
        runS = fmaf(runS, sc_, e_);                                            \
        _Pragma("unroll")                                                      \
        for (int j = 0; j < 4; j++) {                                          \
            tacc[j].x = fmaf(tacc[j].x, sc_, e_ * m[j].x);                     \
            tacc[j].y = fmaf(tacc[j].y, sc_, e_ * m[j].y);                     \
            tacc[j].z = fmaf(tacc[j].z, sc_, e_ * m[j].z);                     \
            tacc[j].w = fmaf(tacc[j].w, sc_, e_ * m[j].w);                     \
        }                                                                      \
        runM = newM_;                                                          \
    }

// FAST (P == I): s = 0.5 * sum m*(v-m)   (4 parallel FMA chains)
#define FAST_SCORE_UPDATE()                                                    \
    {                                                                          \
        float pa = 0.f, pb = 0.f, pc2 = 0.f, pd = 0.f;                         \
        _Pragma("unroll")                                                      \
        for (int j = 0; j < 4; j++) {                                          \
            pa  = fmaf(m[j].x, vr[j].x - m[j].x, pa);                          \
            pb  = fmaf(m[j].y, vr[j].y - m[j].y, pb);                          \
            pc2 = fmaf(m[j].z, vr[j].z - m[j].z, pc2);                         \
            pd  = fmaf(m[j].w, vr[j].w - m[j].w, pd);                          \
        }                                                                      \
        float p_ = (pa + pb) + (pc2 + pd);                                     \
        REDUCE16(p_)                                                           \
        ONLINE_UPDATE(0.5f * p_)                                               \
    }

// SLOW (general P): s = 0.5 * (m . v) - Cn[row]
#define SLOW_SCORE_UPDATE(CV)                                                  \
    {                                                                          \
        float pa = 0.f, pb = 0.f, pc2 = 0.f, pd = 0.f;                         \
        _Pragma("unroll")                                                      \
        for (int j = 0; j < 4; j++) {                                          \
            pa  = fmaf(m[j].x, vr[j].x, pa);                                   \
            pb  = fmaf(m[j].y, vr[j].y, pb);                                   \
            pc2 = fmaf(m[j].z, vr[j].z, pc2);                                  \
            pd  = fmaf(m[j].w, vr[j].w, pd);                                   \
        }                                                                      \
        float p_ = (pa + pb) + (pc2 + pd);                                     \
        REDUCE16(p_)                                                           \
        ONLINE_UPDATE(0.5f * p_ - (CV))                                        \
    }

// ---------------------------------------------------------------------------
// Fallback-path per-row score (uses srows LDS; only compiled in fallback
// kernels which declare srows/flg/wave/g/q/P).
// ---------------------------------------------------------------------------
#define SCORE_AND_UPDATE()                                                     \
    {                                                                          \
        float p_ = 0.f;                                                        \
        _Pragma("unroll")                                                      \
        for (int j = 0; j < 4; j++) {                                          \
            p_ += m[j].x * (vr[j].x - m[j].x);                                 \
            p_ += m[j].y * (vr[j].y - m[j].y);                                 \
            p_ += m[j].z * (vr[j].z - m[j].z);                                 \
            p_ += m[j].w * (vr[j].w - m[j].w);                                 \
        }                                                                      \
        p_ += __shfl_xor(p_, 1, 64);                                           \
        p_ += __shfl_xor(p_, 2, 64);                                           \
        p_ += __shfl_xor(p_, 4, 64);                                           \
        p_ += __shfl_xor(p_, 8, 64);                                           \
        float s_ = 0.5f * p_;                                                  \
        if (flg) {                                                             \
            __syncthreads();                                                   \
            _Pragma("unroll")                                                  \
            for (int jj = 0; jj < 2; jj++)                                     \
                _Pragma("unroll")                                              \
                for (int h = 0; h < 2; h++)                                    \
                    ((float4*)&srows[wave][g][0])[q * 2 + 32 * jj + h] =       \
                        m[jj * 2 + h];                                         \
            __syncthreads();                                                   \
            float dl = 0.f;                                                    \
            for (int k = 0; k < 16; k++) {                                     \
                const int d_ = q * 16 + k;                                     \
                const float md = srows[wave][g][d_];                           \
                float pm = 0.f;                                                \
                for (int e = 0; e < D_; e++)                                   \
                    pm += P[d_ * D_ + e] * srows[wave][g][e];                  \
                dl += md * (md - pm);                                          \
            }                                                                  \
            dl += __shfl_xor(dl, 1, 64);                                       \
            dl += __shfl_xor(dl, 2, 64);                                       \
            dl += __shfl_xor(dl, 4, 64);                                       \
            dl += __shfl_xor(dl, 8, 64);                                       \
            s_ += 0.5f * dl;                                                   \
        }                                                                      \
        const float newM_ = fmaxf(runM, s_);                                   \
        const float sc_ = __expf(runM - newM_);                                \
        const float e_  = __expf(s_ - newM_);                                  \
        runS = fmaf(runS, sc_, e_);                                            \
        _Pragma("unroll")                                                      \
        for (int j = 0; j < 4; j++) {                                          \
            tacc[j].x = fmaf(tacc[j].x, sc_, e_ * m[j].x);                     \
            tacc[j].y = fmaf(tacc[j].y, sc_, e_ * m[j].y);                     \
            tacc[j].z = fmaf(tacc[j].z, sc_, e_ * m[j].z);                     \
            tacc[j].w = fmaf(tacc[j].w, sc_, e_ * m[j].w);                     \
        }                                                                      \
        runM = newM_;                                                          \
    }

// ---------------------------------------------------------------------------
// Persistent cooperative kernel: all 10 iterations in one launch.
// LDS cut to ~6.2 KB (srows removed -> Cn precompute) so 4 blocks/CU fit;
// __launch_bounds__(256,4) caps VGPR at 128 for the same reason.
// ---------------------------------------------------------------------------
template <bool USE_H, int PARTS_>
__global__ __launch_bounds__(256, 4) void persistent_kernel(
        const float* __restrict__ means, const float* __restrict__ z0,
        const float* __restrict__ P, const int* __restrict__ flag,
        const float* __restrict__ Cn, __half* __restrict__ mh,
        float* __restrict__ pT, float2* __restrict__ pS,
        float* __restrict__ out) {
    constexpr int GRID = 64 * PARTS_;
    constexpr int RPB = N_ / PARTS_;   // rows per block
    constexpr int RPW = RPB / 4;       // rows per wave
    constexpr int NSTEPS = RPW / 4;    // 4 rows (one per 16-lane group) per step
    cg::grid_group grid = cg::this_grid();

    const int gid = blockIdx.x, bb = gid / PARTS_, part = gid % PARTS_;
    const int tid = threadIdx.x, wave = tid >> 6, lane = tid & 63;
    const int q = lane & 15, g = lane >> 4;

    __shared__ __align__(16) float vsh[D_];
    __shared__ __align__(16) float shbuf[4][D_];
    __shared__ __align__(16) float zsh[D_];
    __shared__ float wM[4], wS[4];

    const int flg = *flag;

    // v0 = (P+P^T) z0  (fast path 2*z0)
    {
        const float zd = z0[bb * D_ + tid];
        if (!flg) {
            vsh[tid] = 2.f * zd;
        } else {
            zsh[tid] = zd;
            __syncthreads();
            float vv = 0.f;
            for (int e = 0; e < D_; e++)
                vv += (P[tid * D_ + e] + P[e * D_ + tid]) * zsh[e];
            vsh[tid] = vv;
        }
        __syncthreads();
    }

    const size_t wrowbase = (size_t)bb * N_ + (size_t)part * RPB + (size_t)wave * RPW;

    for (int t = 0; t < 10; t++) {
        float4 vr[4];   // vr[jj*2+h] covers d = q*8 + 128*jj + 4*h
        #pragma unroll
        for (int jj = 0; jj < 2; jj++)
            #pragma unroll
            for (int h = 0; h < 2; h++)
                vr[jj * 2 + h] = ((const float4*)vsh)[q * 2 + 32 * jj + h];

        float runM = -INFINITY, runS = 0.f;
        float4 tacc[4];
        #pragma unroll
        for (int j = 0; j < 4; j++) tacc[j] = make_float4(0.f, 0.f, 0.f, 0.f);

        if (!flg) {
            // ================= FAST PATH (P == I) ========================
            if (USE_H && t > 0) {
                // f16 stream with depth-4 software pipeline (ring in regs,
                // chunk-unrolled so ring indices are compile-time).
                const __half* wb = mh + wrowbase * D_;
                constexpr int PF = 4;
                float4 pf0[PF], pf1[PF];
                #pragma unroll
                for (int i = 0; i < PF; i++) {
                    const int rr = (i < NSTEPS ? i : NSTEPS - 1) * 4 + g;
                    const __half* rp = wb + (size_t)rr * D_;
                    pf0[i] = ((const float4*)rp)[q];
                    pf1[i] = ((const float4*)rp)[q + 16];
                }
                for (int base = 0; base < NSTEPS; base += PF) {
                    #pragma unroll
                    for (int k = 0; k < PF; k++) {
                        const int step = base + k;
                        const float4 r0 = pf0[k], r1 = pf1[k];
                        const int ps = (step + PF < NSTEPS) ? step + PF
                                                            : NSTEPS - 1;
                        const __half* rp = wb + (size_t)(ps * 4 + g) * D_;
                        pf0[k] = ((const float4*)rp)[q];
                        pf1[k] = ((const float4*)rp)[q + 16];
                        float4 m[4];
                        cvt_h8(r0, r1, m);
                        FAST_SCORE_UPDATE()
                    }
                }
            } else {
                // f32 (t==0 with f16 write-out, or !USE_H every t).
                const float* wb = means + wrowbase * D_;
                float4 m[4];
                {
                    const float4* rp = (const float4*)(wb + (size_t)g * D_);
                    if (USE_H) {
                        m[0] = nt_load4(rp + q * 2);
                        m[1] = nt_load4(rp + q * 2 + 1);
                        m[2] = nt_load4(rp + q * 2 + 32);
                        m[3] = nt_load4(rp + q * 2 + 33);
                    } else {
                        m[0] = rp[q * 2];     m[1] = rp[q * 2 + 1];
                        m[2] = rp[q * 2 + 32]; m[3] = rp[q * 2 + 33];
                    }
                }
                #pragma unroll 2
                for (int step = 0; step < NSTEPS; step++) {
                    const int pr = ((step + 1 < NSTEPS) ? step + 1 : step) * 4 + g;
                    const float4* rpn = (const float4*)(wb + (size_t)pr * D_);
                    float4 n0, n1, n2, n3;
                    if (USE_H) {
                        n0 = nt_load4(rpn + q * 2);
                        n1 = nt_load4(rpn + q * 2 + 1);
                        n2 = nt_load4(rpn + q * 2 + 32);
                        n3 = nt_load4(rpn + q * 2 + 33);
                    } else {
                        n0 = rpn[q * 2];     n1 = rpn[q * 2 + 1];
                        n2 = rpn[q * 2 + 32]; n3 = rpn[q * 2 + 33];
                    }
                    if (USE_H && t == 0) {
                        const int r = step * 4 + g;
                        __half* hp = mh + (wrowbase + r) * D_;
                        #pragma unroll
                        for (int jj = 0; jj < 2; jj++) {
                            union { uint4 u4; __half2 h2[4]; } pk;
                            pk.h2[0] = __floats2half2_rn(m[jj*2].x,   m[jj*2].y);
                            pk.h2[1] = __floats2half2_rn(m[jj*2].z,   m[jj*2].w);
                            pk.h2[2] = __floats2half2_rn(m[jj*2+1].x, m[jj*2+1].y);
                            pk.h2[3] = __floats2half2_rn(m[jj*2+1].z, m[jj*2+1].w);
                            *(uint4*)(hp + q * 8 + 128 * jj) = pk.u4;
                        }
                    }
                    FAST_SCORE_UPDATE()
                    m[0] = n0; m[1] = n1; m[2] = n2; m[3] = n3;
                }
            }
        } else {
            // ============ SLOW PATH (general P): s = 0.5 m.v - Cn =========
            if (USE_H && t > 0) {
                for (int step = 0; step < NSTEPS; step++) {
                    const int r = step * 4 + g;
                    const __half* rp = mh + (wrowbase + r) * D_;
                    const float4 r0 = ((const float4*)rp)[q];
                    const float4 r1 = ((const float4*)rp)[q + 16];
                    float4 m[4];
                    cvt_h8(r0, r1, m);
                    const float cv = Cn[wrowbase + r];
                    SLOW_SCORE_UPDATE(cv)
                }
            } else {
                for (int step = 0; step < NSTEPS; step++) {
                    const int r = step * 4 + g;
                    const float* rp = means + (wrowbase + r) * D_;
                    float4 m[4];
                    #pragma unroll
                    for (int jj = 0; jj < 2; jj++)
                        #pragma unroll
                        for (int h = 0; h < 2; h++)
                            m[jj * 2 + h] = ((const float4*)rp)[q * 2 + 32 * jj + h];
                    if (USE_H && t == 0) {
                        __half* hp = mh + (wrowbase + r) * D_;
                        #pragma unroll
                        for (int jj = 0; jj < 2; jj++) {
                            union { uint4 u4; __half2 h2[4]; } pk;
                            pk.h2[0] = __floats2half2_rn(m[jj*2].x,   m[jj*2].y);
                            pk.h2[1] = __floats2half2_rn(m[jj*2].z,   m[jj*2].w);
                            pk.h2[2] = __floats2half2_rn(m[jj*2+1].x, m[jj*2+1].y);
                            pk.h2[3] = __floats2half2_rn(m[jj*2+1].z, m[jj*2+1].w);
                            *(uint4*)(hp + q * 8 + 128 * jj) = pk.u4;
                        }
                    }
                    const float cv = Cn[wrowbase + r];
                    SLOW_SCORE_UPDATE(cv)
                }
            }
        }

        // ---- epilogue: combine 4 lane-groups (xor 16/32), then 4 waves ----
        float Mw = runM;
        Mw = fmaxf(Mw, __shfl_xor(Mw, 16, 64));
        Mw = fmaxf(Mw, __shfl_xor(Mw, 32, 64));
        const float aw = __expf(runM - Mw);
        float Sa = runS * aw;
        Sa += __shfl_xor(Sa, 16, 64);
        Sa += __shfl_xor(Sa, 32, 64);
        #pragma unroll
        for (int j = 0; j < 4; j++) {
            tacc[j].x *= aw; tacc[j].y *= aw; tacc[j].z *= aw; tacc[j].w *= aw;
            tacc[j].x += __shfl_xor(tacc[j].x, 16, 64);
            tacc[j].y += __shfl_xor(tacc[j].y, 16, 64);
            tacc[j].z += __shfl_xor(tacc[j].z, 16, 64);
            tacc[j].w += __shfl_xor(tacc[j].w, 16, 64);
            tacc[j].x += __shfl_xor(tacc[j].x, 32, 64);
            tacc[j].y += __shfl_xor(tacc[j].y, 32, 64);
            tacc[j].z += __shfl_xor(tacc[j].z, 32, 64);
            tacc[j].w += __shfl_xor(tacc[j].w, 32, 64);
        }
        if (lane < 16) {
            #pragma unroll
            for (int j = 0; j < 4; j++)
                ((float4*)shbuf[wave])[q * 2 + 32 * (j >> 1) + (j & 1)] = tacc[j];
        }
        if (lane == 0) { wM[wave] = Mw; wS[wave] = Sa; }
        __syncthreads();
        const float Mb = fmaxf(fmaxf(wM[0], wM[1]), fmaxf(wM[2], wM[3]));
        const float a0 = __expf(wM[0] - Mb), a1 = __expf(wM[1] - Mb),
                    a2 = __expf(wM[2] - Mb), a3 = __expf(wM[3] - Mb);
        const float Tc = a0 * shbuf[0][tid] + a1 * shbuf[1][tid] +
                         a2 * shbuf[2][tid] + a3 * shbuf[3][tid];
        const int buf = t & 1;
        pT[((size_t)buf * GRID + gid) * D_ + tid] = Tc;
        if (tid == 0)
            pS[buf * GRID + gid] = make_float2(
                Mb, a0 * wS[0] + a1 * wS[1] + a2 * wS[2] + a3 * wS[3]);

        grid.sync();

        // ---- combine PARTS_ partials for my bb (redundant per part) ----
        float Mg = -INFINITY;
        float2 stl[PARTS_];
        #pragma unroll
        for (int pI = 0; pI < PARTS_; pI++) {
            stl[pI] = pS[buf * GRID + bb * PARTS_ + pI];
            Mg = fmaxf(Mg, stl[pI].x);
        }
        float Sg = 0.f, accg = 0.f;
        #pragma unroll
        for (int pI = 0; pI < PARTS_; pI++) {
            const float a = __expf(stl[pI].x - Mg);
            Sg += a * stl[pI].y;
            accg += a * pT[((size_t)buf * GRID + bb * PARTS_ + pI) * D_ + tid];
        }
        const float zv = accg / Sg;
        if (t == 9) {
            if (part == 0) out[bb * D_ + tid] = zv;
        } else {
            if (!flg) {
                vsh[tid] = 2.f * zv;
            } else {
                zsh[tid] = zv;
                __syncthreads();
                float vv = 0.f;
                for (int e = 0; e < D_; e++)
                    vv += (P[tid * D_ + e] + P[e * D_ + tid]) * zsh[e];
                vsh[tid] = vv;
            }
            __syncthreads();
        }
    }
}

// ===========================================================================
// Fallback multi-kernel path (round-4, proven) — used if workspace or
// cooperative occupancy is insufficient.
// ===========================================================================
__global__ __launch_bounds__(256) void vcalc_kernel(const float* __restrict__ P,
                                                    const float* __restrict__ z,
                                                    const int* __restrict__ flag,
                                                    float* __restrict__ v) {
    __shared__ float zsh[D_];
    const int b = blockIdx.x, d = threadIdx.x;
    const float zd = z[b * D_ + d];
    if (*flag == 0) {
        v[b * D_ + d] = 2.0f * zd;
        return;
    }
    zsh[d] = zd;
    __syncthreads();
    float acc = 0.f;
    for (int e = 0; e < D_; e++)
        acc += (P[d * D_ + e] + P[e * D_ + d]) * zsh[e];
    v[b * D_ + d] = acc;
}

template <bool WRITE_H>
__global__ __launch_bounds__(256) void fused_f32_kernel(const float* __restrict__ means,
                                                        const float* __restrict__ v,
                                                        const float* __restrict__ P,
                                                        const int* __restrict__ flag,
                                                        __half* __restrict__ mh,
                                                        float* __restrict__ Tbuf,
                                                        float2* __restrict__ stats) {
    const int b = blockIdx.y, chunk = blockIdx.x;
    const int tid = threadIdx.x, wave = tid >> 6, lane = tid & 63;
    const int q = lane & 15, g = lane >> 4;
    __shared__ __align__(16) float vsh[D_];
    __shared__ __align__(16) float shbuf[4][D_];
    __shared__ __align__(16) float srows[4][4][D_];
    __shared__ float wM[4], wS[4];
    vsh[tid] = v[b * D_ + tid];
    __syncthreads();
    float4 vr[4];
    #pragma unroll
    for (int jj = 0; jj < 2; jj++)
        #pragma unroll
        for (int h = 0; h < 2; h++)
            vr[jj * 2 + h] = ((const float4*)vsh)[q * 2 + 32 * jj + h];
    const int flg = *flag;

    float runM = -INFINITY, runS = 0.f;
    float4 tacc[4];
    #pragma unroll
    for (int j = 0; j < 4; j++) tacc[j] = make_float4(0.f, 0.f, 0.f, 0.f);

    const size_t rowbase = (size_t)b * N_ + (size_t)chunk * NPB + (size_t)wave * NPW;

    for (int step = 0; step < NSTEP; step++) {
        const int r = step * 4 + g;
        const float* rp = means + (rowbase + r) * D_;
        float4 m[4];
        #pragma unroll
        for (int jj = 0; jj < 2; jj++)
            #pragma unroll
            for (int h = 0; h < 2; h++)
                m[jj * 2 + h] = ((const float4*)rp)[q * 2 + 32 * jj + h];
        if (WRITE_H) {
            __half* hp = mh + (rowbase + r) * D_;
            #pragma unroll
            for (int jj = 0; jj < 2; jj++) {
                union { uint4 u4; __half2 h2[4]; } pk;
                pk.h2[0] = __floats2half2_rn(m[jj*2].x,   m[jj*2].y);
                pk.h2[1] = __floats2half2_rn(m[jj*2].z,   m[jj*2].w);
                pk.h2[2] = __floats2half2_rn(m[jj*2+1].x, m[jj*2+1].y);
                pk.h2[3] = __floats2half2_rn(m[jj*2+1].z, m[jj*2+1].w);
                *(uint4*)(hp + q * 8 + 128 * jj) = pk.u4;
            }
        }
        SCORE_AND_UPDATE()
    }

    float Mw = runM;
    Mw = fmaxf(Mw, __shfl_xor(Mw, 16, 64));
    Mw = fmaxf(Mw, __shfl_xor(Mw, 32, 64));
    const float aw = __expf(runM - Mw);
    float Sa = runS * aw;
    Sa += __shfl_xor(Sa, 16, 64);
    Sa += __shfl_xor(Sa, 32, 64);
    #pragma unroll
    for (int j = 0; j < 4; j++) {
        tacc[j].x *= aw; tacc[j].y *= aw; tacc[j].z *= aw; tacc[j].w *= aw;
        tacc[j].x += __shfl_xor(tacc[j].x, 16, 64);
        tacc[j].y += __shfl_xor(tacc[j].y, 16, 64);
        tacc[j].z += __shfl_xor(tacc[j].z, 16, 64);
        tacc[j].w += __shfl_xor(tacc[j].w, 16, 64);
        tacc[j].x += __shfl_xor(tacc[j].x, 32, 64);
        tacc[j].y += __shfl_xor(tacc[j].y, 32, 64);
        tacc[j].z += __shfl_xor(tacc[j].z, 32, 64);
        tacc[j].w += __shfl_xor(tacc[j].w, 32, 64);
    }
    if (lane < 16) {
        #pragma unroll
        for (int j = 0; j < 4; j++)
            ((float4*)shbuf[wave])[q * 2 + 32 * (j >> 1) + (j & 1)] = tacc[j];
    }
    if (lane == 0) { wM[wave] = Mw; wS[wave] = Sa; }
    __syncthreads();
    const float Mb = fmaxf(fmaxf(wM[0], wM[1]), fmaxf(wM[2], wM[3]));
    const float a0 = __expf(wM[0] - Mb), a1 = __expf(wM[1] - Mb),
                a2 = __expf(wM[2] - Mb), a3 = __expf(wM[3] - Mb);
    const float Tc = a0 * shbuf[0][tid] + a1 * shbuf[1][tid] +
                     a2 * shbuf[2][tid] + a3 * shbuf[3][tid];
    Tbuf[((size_t)(b * NCH + chunk)) * D_ + tid] = Tc;
    if (tid == 0)
        stats[b * NCH + chunk] = make_float2(
            Mb, a0 * wS[0] + a1 * wS[1] + a2 * wS[2] + a3 * wS[3]);
}

__global__ __launch_bounds__(256) void fused_f16_kernel(const __half* __restrict__ mh,
                                                        const float* __restrict__ v,
                                                        const float* __restrict__ P,
                                                        const int* __restrict__ flag,
                                                        float* __restrict__ Tbuf,
                                                        float2* __restrict__ stats) {
    const int b = blockIdx.y, chunk = blockIdx.x;
    const int tid = threadIdx.x, wave = tid >> 6, lane = tid & 63;
    const int q = lane & 15, g = lane >> 4;
    __shared__ __align__(16) float vsh[D_];
    __shared__ __align__(16) float shbuf[4][D_];
    __shared__ __align__(16) float srows[4][4][D_];
    __shared__ float wM[4], wS[4];
    vsh[tid] = v[b * D_ + tid];
    __syncthreads();
    float4 vr[4];
    #pragma unroll
    for (int jj = 0; jj < 2; jj++)
        #pragma unroll
        for (int h = 0; h < 2; h++)
            vr[jj * 2 + h] = ((const float4*)vsh)[q * 2 + 32 * jj + h];
    const int flg = *flag;

    float runM = -INFINITY, runS = 0.f;
    float4 tacc[4];
    #pragma unroll
    for (int j = 0; j < 4; j++) tacc[j] = make_float4(0.f, 0.f, 0.f, 0.f);

    const size_t rowbase = (size_t)b * N_ + (size_t)chunk * NPB + (size_t)wave * NPW;

    for (int step = 0; step < NSTEP; step++) {
        const int r = step * 4 + g;
        const __half* rp = mh + (rowbase + r) * D_;
        float4 m[4];
        #pragma unroll
        for (int jj = 0; jj < 2; jj++) {
            float4 raw = ((const float4*)rp)[q + 16 * jj];
            const __half2* hp2 = (const __half2*)&raw;
            const float2 f0 = __half22float2(hp2[0]);
            const float2 f1 = __half22float2(hp2[1]);
            const float2 f2 = __half22float2(hp2[2]);
            const float2 f3 = __half22float2(hp2[3]);
            m[jj * 2 + 0] = make_float4(f0.x, f0.y, f1.x, f1.y);
            m[jj * 2 + 1] = make_float4(f2.x, f2.y, f3.x, f3.y);
        }
        SCORE_AND_UPDATE()
    }

    float Mw = runM;
    Mw = fmaxf(Mw, __shfl_xor(Mw, 16, 64));
    Mw = fmaxf(Mw, __shfl_xor(Mw, 32, 64));
    const float aw = __expf(runM - Mw);
    float Sa = runS * aw;
    Sa += __shfl_xor(Sa, 16, 64);
    Sa += __shfl_xor(Sa, 32, 64);
    #pragma unroll
    for (int j = 0; j < 4; j++) {
        tacc[j].x *= aw; tacc[j].y *= aw; tacc[j].z *= aw; tacc[j].w *= aw;
        tacc[j].x += __shfl_xor(tacc[j].x, 16, 64);
        tacc[j].y += __shfl_xor(tacc[j].y, 16, 64);
        tacc[j].z += __shfl_xor(tacc[j].z, 16, 64);
        tacc[j].w += __shfl_xor(tacc[j].w, 16, 64);
        tacc[j].x += __shfl_xor(tacc[j].x, 32, 64);
        tacc[j].y += __shfl_xor(tacc[j].y, 32, 64);
        tacc[j].z += __shfl_xor(tacc[j].z, 32, 64);
        tacc[j].w += __shfl_xor(tacc[j].w, 32, 64);
    }
    if (lane < 16) {
        #pragma unroll
        for (int j = 0; j < 4; j++)
            ((float4*)shbuf[wave])[q * 2 + 32 * (j >> 1) + (j & 1)] = tacc[j];
    }
    if (lane == 0) { wM[wave] = Mw; wS[wave] = Sa; }
    __syncthreads();
    const float Mb = fmaxf(fmaxf(wM[0], wM[1]), fmaxf(wM[2], wM[3]));
    const float a0 = __expf(wM[0] - Mb), a1 = __expf(wM[1] - Mb),
                a2 = __expf(wM[2] - Mb), a3 = __expf(wM[3] - Mb);
    const float Tc = a0 * shbuf[0][tid] + a1 * shbuf[1][tid] +
                     a2 * shbuf[2][tid] + a3 * shbuf[3][tid];
    Tbuf[((size_t)(b * NCH + chunk)) * D_ + tid] = Tc;
    if (tid == 0)
        stats[b * NCH + chunk] = make_float2(
            Mb, a0 * wS[0] + a1 * wS[1] + a2 * wS[2] + a3 * wS[3]);
}

__global__ __launch_bounds__(256) void combine_kernel(const float* __restrict__ Tbuf,
                                                      const float2* __restrict__ stats,
                                                      const float* __restrict__ P,
                                                      const int* __restrict__ flag,
                                                      float* __restrict__ v,
                                                      float* __restrict__ out) {
    const int b = blockIdx.x, d = threadIdx.x;
    __shared__ float Msh[NCH], Ssh[NCH];
    __shared__ float zsh[D_];
    if (d < NCH) {
        const float2 st = stats[b * NCH + d];
        Msh[d] = st.x; Ssh[d] = st.y;
    }
    __syncthreads();
    float M = -INFINITY;
    for (int c = 0; c < NCH; c++) M = fmaxf(M, Msh[c]);
    float S = 0.f, acc = 0.f;
    for (int c = 0; c < NCH; c++) {
        const float a = __expf(Msh[c] - M);
        S += a * Ssh[c];
        acc += a * Tbuf[((size_t)(b * NCH + c)) * D_ + d];
    }
    const float z = acc / S;
    if (out) out[b * D_ + d] = z;
    if (*flag == 0) {
        v[b * D_ + d] = 2.0f * z;
        return;
    }
    zsh[d] = z;
    __syncthreads();
    float vv = 0.f;
    for (int e = 0; e < D_; e++)
        vv += (P[d * D_ + e] + P[e * D_ + d]) * zsh[e];
    v[b * D_ + d] = vv;
}

extern "C" void kernel_launch(void* const* d_in, const int* in_sizes, int n_in,
                              void* d_out, int out_size, void* d_ws, size_t ws_size,
                              hipStream_t stream) {
    // inputs: 0=x (unused), 1=z, 2=means, 3=precision, 4=iterations(=10)
    const float* z0    = (const float*)d_in[1];
    const float* means = (const float*)d_in[2];
    const float* P     = (const float*)d_in[3];
    float* out = (float*)d_out;

    char* ws = (char*)d_ws;
    size_t off = 0;
    int*    flag  = (int*)ws;                     off = 256;
    float*  v     = (float*)(ws + off);           off += (size_t)B_ * D_ * 4;
    float*  Tbuf  = (float*)(ws + off);           off += (size_t)B_ * NCH * D_ * 4;
    float2* stats = (float2*)(ws + off);          off += (size_t)B_ * NCH * 8;
    off = (off + 255) & ~(size_t)255;
    float*  pT    = (float*)(ws + off);           off += 2ull * 1024 * D_ * 4;
    float2* pS    = (float2*)(ws + off);          off += 2ull * 1024 * 8;
    off = (off + 255) & ~(size_t)255;
    float*  Cn    = (float*)(ws + off);           off += (size_t)B_ * N_ * 4;
    off = (off + 255) & ~(size_t)255;
    __half* mh    = (__half*)(ws + off);
    const size_t coop_need  = off;                               // ~7.4 MiB
    const size_t full_need  = off + (size_t)B_ * N_ * D_ * 2;    // + 128 MiB
    const bool use_h = (ws_size >= full_need);
    const bool ws_ok = (ws_size >= coop_need);

    flag_kernel<<<dim3(1), dim3(256), 0, stream>>>(P, flag);

    // ---- cooperative persistent path (preferred) ----
    if (ws_ok) {
        // Cn precompute (no-op when P == I)
        cn_kernel<<<dim3(B_ * N_ / CNR), dim3(256), 0, stream>>>(means, P, flag, Cn);

        void* args[] = {(void*)&means, (void*)&z0, (void*)&P, (void*)&flag,
                        (void*)&Cn, (void*)&mh, (void*)&pT, (void*)&pS, (void*)&out};
        int nb = 0;
        if (use_h) {
            if (hipOccupancyMaxActiveBlocksPerMultiprocessor(
                    &nb, persistent_kernel<true, 16>, 256, 0) == hipSuccess && nb >= 4) {
                if (hipLaunchCooperativeKernel(persistent_kernel<true, 16>,
                        dim3(1024), dim3(256), args, 0, stream) == hipSuccess)
                    return;
            }
            nb = 0;
            if (hipOccupancyMaxActiveBlocksPerMultiprocessor(
                    &nb, persistent_kernel<true, 8>, 256, 0) == hipSuccess && nb >= 2) {
                if (hipLaunchCooperativeKernel(persistent_kernel<true, 8>,
                        dim3(512), dim3(256), args, 0, stream) == hipSuccess)
                    return;
            }
        } else {
            if (hipOccupancyMaxActiveBlocksPerMultiprocessor(
                    &nb, persistent_kernel<false, 16>, 256, 0) == hipSuccess && nb >= 4) {
                if (hipLaunchCooperativeKernel(persistent_kernel<false, 16>,
                        dim3(1024), dim3(256), args, 0, stream) == hipSuccess)
                    return;
            }
            nb = 0;
            if (hipOccupancyMaxActiveBlocksPerMultiprocessor(
                    &nb, persistent_kernel<false, 8>, 256, 0) == hipSuccess && nb >= 2) {
                if (hipLaunchCooperativeKernel(persistent_kernel<false, 8>,
                        dim3(512), dim3(256), args, 0, stream) == hipSuccess)
                    return;
            }
        }
    }

    // ---- fallback multi-kernel path (round-4) ----
    vcalc_kernel<<<dim3(B_), dim3(256), 0, stream>>>(P, z0, flag, v);
    if (use_h) {
        fused_f32_kernel<true><<<dim3(NCH, B_), dim3(256), 0, stream>>>(
            means, v, P, flag, mh, Tbuf, stats);
        combine_kernel<<<dim3(B_), dim3(256), 0, stream>>>(Tbuf, stats, P, flag, v, nullptr);
        for (int t = 1; t < 10; t++) {
            fused_f16_kernel<<<dim3(NCH, B_), dim3(256), 0, stream>>>(
                mh, v, P, flag, Tbuf, stats);
            combine_kernel<<<dim3(B_), dim3(256), 0, stream>>>(Tbuf, stats, P, flag, v,
                                                               (t == 9) ? out : nullptr);
        }
    } else {
        for (int t = 0; t < 10; t++) {
            fused_f32_kernel<false><<<dim3(NCH, B_), dim3(256), 0, stream>>>(
                means, v, P, flag, nullptr, Tbuf, stats);
            combine_kernel<<<dim3(B_), dim3(256), 0, stream>>>(Tbuf, stats, P, flag, v,
                                                               (t == 9) ? out : nullptr);
        }
    }
}

// Round 3
// 1203.184 us; speedup vs baseline: 1.2137x; 1.2137x over previous
//
#include <hip/hip_runtime.h>
#include <hip/hip_fp16.h>
#include <hip/hip_cooperative_groups.h>
#include <math.h>

namespace cg = cooperative_groups;

constexpr int B_ = 64;
constexpr int N_ = 4096;
constexpr int D_ = 256;
constexpr int NCH = 64;            // fallback path: chunks per batch row
constexpr int NPB = N_ / NCH;      // 64 rows per block
constexpr int NPW = NPB / 4;       // 16 rows per wave
constexpr int NSTEP = NPW / 4;     // fallback: 4 steps of 4 rows
constexpr int CNR = 16;            // rows per block in cn_kernel

// nontemporal float4 load (ext_vector to satisfy the builtin's type rules)
typedef float f4v __attribute__((ext_vector_type(4)));
__device__ __forceinline__ float4 nt_load4(const float4* p) {
    f4v v = __builtin_nontemporal_load((const f4v*)p);
    return make_float4(v.x, v.y, v.z, v.w);
}

// unpack 8 halves (two float4-sized raw loads) into 4 float4
__device__ __forceinline__ void cvt_h8(const float4 r0, const float4 r1, float4 m[4]) {
    const __half2* h0 = (const __half2*)&r0;
    const float2 f0 = __half22float2(h0[0]);
    const float2 f1 = __half22float2(h0[1]);
    const float2 f2 = __half22float2(h0[2]);
    const float2 f3 = __half22float2(h0[3]);
    m[0] = make_float4(f0.x, f0.y, f1.x, f1.y);
    m[1] = make_float4(f2.x, f2.y, f3.x, f3.y);
    const __half2* h1 = (const __half2*)&r1;
    const float2 g0 = __half22float2(h1[0]);
    const float2 g1 = __half22float2(h1[1]);
    const float2 g2 = __half22float2(h1[2]);
    const float2 g3 = __half22float2(h1[3]);
    m[2] = make_float4(g0.x, g0.y, g1.x, g1.y);
    m[3] = make_float4(g2.x, g2.y, g3.x, g3.y);
}

// ---------------------------------------------------------------------------
// flag: is precision == I?  0 -> fast paths everywhere.
// ---------------------------------------------------------------------------
__global__ __launch_bounds__(256) void flag_kernel(const float* __restrict__ P,
                                                   int* __restrict__ flag) {
    __shared__ int sh[256];
    const int tid = threadIdx.x;
    int bad = 0;
    for (int i = tid; i < D_ * D_; i += 256) {
        const int r = i >> 8, c = i & 255;
        const float expect = (r == c) ? 1.0f : 0.0f;
        bad |= (P[i] != expect) ? 1 : 0;
    }
    sh[tid] = bad;
    __syncthreads();
    for (int s = 128; s > 0; s >>= 1) {
        if (tid < s) sh[tid] |= sh[tid + s];
        __syncthreads();
    }
    if (tid == 0) *flag = sh[0];
}

// ---------------------------------------------------------------------------
// Cn[row] = 0.5 * m_row^T P m_row  (iteration-invariant general-P correction).
// Only meaningful when flag != 0; early-exits otherwise. 16 rows per block.
// ---------------------------------------------------------------------------
__global__ __launch_bounds__(256) void cn_kernel(const float* __restrict__ means,
                                                 const float* __restrict__ P,
                                                 const int* __restrict__ flag,
                                                 float* __restrict__ Cn) {
    if (*flag == 0) return;
    const int row0 = blockIdx.x * CNR;
    const int d = threadIdx.x;
    __shared__ __align__(16) float msh[CNR][D_];
    __shared__ float red[CNR][4];
    #pragma unroll
    for (int i = 0; i < CNR; i++)
        msh[i][d] = means[(size_t)(row0 + i) * D_ + d];
    __syncthreads();
    float acc[CNR];
    #pragma unroll
    for (int r = 0; r < CNR; r++) acc[r] = 0.f;
    for (int e = 0; e < D_; e++) {
        const float pde = P[d * D_ + e];
        #pragma unroll
        for (int r = 0; r < CNR; r++) acc[r] = fmaf(pde, msh[r][e], acc[r]);
    }
    const int lane = d & 63, wv = d >> 6;
    #pragma unroll
    for (int r = 0; r < CNR; r++) {
        float pv = msh[r][d] * acc[r];
        for (int s = 1; s < 64; s <<= 1) pv += __shfl_xor(pv, s, 64);
        if (lane == 0) red[r][wv] = pv;
    }
    __syncthreads();
    if (d < CNR)
        Cn[row0 + d] = 0.5f * (red[d][0] + red[d][1] + red[d][2] + red[d][3]);
}

// ---------------------------------------------------------------------------
// Online-softmax building blocks for the persistent kernel (no LDS, no bar).
// Expect in scope: m[4], vr[4], runM, runS, tacc[4].
// ---------------------------------------------------------------------------
#define REDUCE16(P)                                                            \
    P += __shfl_xor(P, 1, 64);                                                 \
    P += __shfl_xor(P, 2, 64);                                                 \
    P += __shfl_xor(P, 4, 64);                                                 \
    P += __shfl_xor(P, 8, 64);

#define ONLINE_UPDATE(SEXPR)                                                   \
    {                                                                          \
        const float s_ = (SEXPR);                                              \
        const float newM_ = fmaxf(runM, s_);                                   \
        const float sc_ = __expf(runM - newM_);                                \
        const float e_  = __expf(s_ - newM_);                                  \
        runS = fmaf(runS, sc_, e_);                                            \
        _Pragma("unroll")                                                      \
        for (int j = 0; j < 4; j++) {                                          \
            tacc[j].x = fmaf(tacc[j].x, sc_, e_ * m[j].x);                     \
            tacc[j].y = fmaf(tacc[j].y, sc_, e_ * m[j].y);                     \
            tacc[j].z = fmaf(tacc[j].z, sc_, e_ * m[j].z);                     \
            tacc[j].w = fmaf(tacc[j].w, sc_, e_ * m[j].w);                     \
        }                                                                      \
        runM = newM_;                                                          \
    }

// FAST (P == I): s = 0.5 * sum m*(v-m)   (4 parallel FMA chains)
#define FAST_SCORE_UPDATE()                                                    \
    {                                                                          \
        float pa = 0.f, pb = 0.f, pc2 = 0.f, pd = 0.f;                         \
        _Pragma("unroll")                                                      \
        for (int j = 0; j < 4; j++) {                                          \
            pa  = fmaf(m[j].x, vr[j].x - m[j].x, pa);                          \
            pb  = fmaf(m[j].y, vr[j].y - m[j].y, pb);                          \
            pc2 = fmaf(m[j].z, vr[j].z - m[j].z, pc2);                         \
            pd  = fmaf(m[j].w, vr[j].w - m[j].w, pd);                          \
        }                                                                      \
        float p_ = (pa + pb) + (pc2 + pd);                                     \
        REDUCE16(p_)                                                           \
        ONLINE_UPDATE(0.5f * p_)                                               \
    }

// SLOW (general P): s = 0.5 * (m . v) - Cn[row]
#define SLOW_SCORE_UPDATE(CV)                                                  \
    {                                                                          \
        float pa = 0.f, pb = 0.f, pc2 = 0.f, pd = 0.f;                         \
        _Pragma("unroll")                                                      \
        for (int j = 0; j < 4; j++) {                                          \
            pa  = fmaf(m[j].x, vr[j].x, pa);                                   \
            pb  = fmaf(m[j].y, vr[j].y, pb);                                   \
            pc2 = fmaf(m[j].z, vr[j].z, pc2);                                  \
            pd  = fmaf(m[j].w, vr[j].w, pd);                                   \
        }                                                                      \
        float p_ = (pa + pb) + (pc2 + pd);                                     \
        REDUCE16(p_)                                                           \
        ONLINE_UPDATE(0.5f * p_ - (CV))                                        \
    }

// ---------------------------------------------------------------------------
// Fallback-path per-row score (uses srows LDS; only compiled in fallback
// kernels which declare srows/flg/wave/g/q/P).
// ---------------------------------------------------------------------------
#define SCORE_AND_UPDATE()                                                     \
    {                                                                          \
        float p_ = 0.f;                                                        \
        _Pragma("unroll")                                                      \
        for (int j = 0; j < 4; j++) {                                          \
            p_ += m[j].x * (vr[j].x - m[j].x);                                 \
            p_ += m[j].y * (vr[j].y - m[j].y);                                 \
            p_ += m[j].z * (vr[j].z - m[j].z);                                 \
            p_ += m[j].w * (vr[j].w - m[j].w);                                 \
        }                                                                      \
        p_ += __shfl_xor(p_, 1, 64);                                           \
        p_ += __shfl_xor(p_, 2, 64);                                           \
        p_ += __shfl_xor(p_, 4, 64);                                           \
        p_ += __shfl_xor(p_, 8, 64);                                           \
        float s_ = 0.5f * p_;                                                  \
        if (flg) {                                                             \
            __syncthreads();                                                   \
            _Pragma("unroll")                                                  \
            for (int jj = 0; jj < 2; jj++)                                     \
                _Pragma("unroll")                                              \
                for (int h = 0; h < 2; h++)                                    \
                    ((float4*)&srows[wave][g][0])[q * 2 + 32 * jj + h] =       \
                        m[jj * 2 + h];                                         \
            __syncthreads();                                                   \
            float dl = 0.f;                                                    \
            for (int k = 0; k < 16; k++) {                                     \
                const int d_ = q * 16 + k;                                     \
                const float md = srows[wave][g][d_];                           \
                float pm = 0.f;                                                \
                for (int e = 0; e < D_; e++)                                   \
                    pm += P[d_ * D_ + e] * srows[wave][g][e];                  \
                dl += md * (md - pm);                                          \
            }                                                                  \
            dl += __shfl_xor(dl, 1, 64);                                       \
            dl += __shfl_xor(dl, 2, 64);                                       \
            dl += __shfl_xor(dl, 4, 64);                                       \
            dl += __shfl_xor(dl, 8, 64);                                       \
            s_ += 0.5f * dl;                                                   \
        }                                                                      \
        const float newM_ = fmaxf(runM, s_);                                   \
        const float sc_ = __expf(runM - newM_);                                \
        const float e_  = __expf(s_ - newM_);                                  \
        runS = fmaf(runS, sc_, e_);                                            \
        _Pragma("unroll")                                                      \
        for (int j = 0; j < 4; j++) {                                          \
            tacc[j].x = fmaf(tacc[j].x, sc_, e_ * m[j].x);                     \
            tacc[j].y = fmaf(tacc[j].y, sc_, e_ * m[j].y);                     \
            tacc[j].z = fmaf(tacc[j].z, sc_, e_ * m[j].z);                     \
            tacc[j].w = fmaf(tacc[j].w, sc_, e_ * m[j].w);                     \
        }                                                                      \
        runM = newM_;                                                          \
    }

// ---------------------------------------------------------------------------
// Persistent cooperative kernel: all 10 iterations in one launch.
// LDS ~6.2 KB, VGPR target <128 so 4 blocks/CU (16 waves/CU) fit.
// f16 main loop: depth-2 software pipeline in NAMED scalars (no arrays ->
// no scratch spill; round-2's PF=4 ring spilled: WRITE_SIZE +331 MB).
// ---------------------------------------------------------------------------
template <bool USE_H, int PARTS_>
__global__ __launch_bounds__(256, 4) void persistent_kernel(
        const float* __restrict__ means, const float* __restrict__ z0,
        const float* __restrict__ P, const int* __restrict__ flag,
        const float* __restrict__ Cn, __half* __restrict__ mh,
        float* __restrict__ pT, float2* __restrict__ pS,
        float* __restrict__ out) {
    constexpr int GRID = 64 * PARTS_;
    constexpr int RPB = N_ / PARTS_;   // rows per block
    constexpr int RPW = RPB / 4;       // rows per wave
    constexpr int NSTEPS = RPW / 4;    // 4 rows (one per 16-lane group) per step
    static_assert(NSTEPS % 2 == 0, "depth-2 pipeline needs even NSTEPS");
    cg::grid_group grid = cg::this_grid();

    const int gid = blockIdx.x, bb = gid / PARTS_, part = gid % PARTS_;
    const int tid = threadIdx.x, wave = tid >> 6, lane = tid & 63;
    const int q = lane & 15, g = lane >> 4;

    __shared__ __align__(16) float vsh[D_];
    __shared__ __align__(16) float shbuf[4][D_];
    __shared__ __align__(16) float zsh[D_];
    __shared__ float wM[4], wS[4];

    const int flg = *flag;

    // v0 = (P+P^T) z0  (fast path 2*z0)
    {
        const float zd = z0[bb * D_ + tid];
        if (!flg) {
            vsh[tid] = 2.f * zd;
        } else {
            zsh[tid] = zd;
            __syncthreads();
            float vv = 0.f;
            for (int e = 0; e < D_; e++)
                vv += (P[tid * D_ + e] + P[e * D_ + tid]) * zsh[e];
            vsh[tid] = vv;
        }
        __syncthreads();
    }

    const size_t wrowbase = (size_t)bb * N_ + (size_t)part * RPB + (size_t)wave * RPW;

    for (int t = 0; t < 10; t++) {
        float4 vr[4];   // vr[jj*2+h] covers d = q*8 + 128*jj + 4*h
        #pragma unroll
        for (int jj = 0; jj < 2; jj++)
            #pragma unroll
            for (int h = 0; h < 2; h++)
                vr[jj * 2 + h] = ((const float4*)vsh)[q * 2 + 32 * jj + h];

        float runM = -INFINITY, runS = 0.f;
        float4 tacc[4];
        #pragma unroll
        for (int j = 0; j < 4; j++) tacc[j] = make_float4(0.f, 0.f, 0.f, 0.f);

        if (!flg) {
            // ================= FAST PATH (P == I) ========================
            if (USE_H && t > 0) {
                // f16 stream, depth-2 pipeline in named scalars.
                const __half* wb = mh + wrowbase * D_;
                // prologue: rows for step 0 (A) and step 1 (B)
                const float4* rpA = (const float4*)(wb + (size_t)(0 * 4 + g) * D_);
                const float4* rpB = (const float4*)(wb + (size_t)(1 * 4 + g) * D_);
                float4 A0 = rpA[q], A1 = rpA[q + 16];
                float4 B0 = rpB[q], B1 = rpB[q + 16];
                for (int step = 0; step < NSTEPS; step += 2) {
                    // issue loads for step+2 before consuming step
                    const int s2 = (step + 2 < NSTEPS) ? step + 2 : step;
                    const float4* rpN = (const float4*)(wb + (size_t)(s2 * 4 + g) * D_);
                    const float4 N0 = rpN[q], N1 = rpN[q + 16];
                    float4 m[4];
                    cvt_h8(A0, A1, m);
                    FAST_SCORE_UPDATE()
                    A0 = N0; A1 = N1;
                    // issue loads for step+3 before consuming step+1
                    const int s3 = (step + 3 < NSTEPS) ? step + 3 : step + 1;
                    const float4* rpM = (const float4*)(wb + (size_t)(s3 * 4 + g) * D_);
                    const float4 M0 = rpM[q], M1 = rpM[q + 16];
                    cvt_h8(B0, B1, m);
                    FAST_SCORE_UPDATE()
                    B0 = M0; B1 = M1;
                }
            } else {
                // f32 (t==0 with f16 write-out, or !USE_H every t), depth-1.
                const float* wb = means + wrowbase * D_;
                float4 m[4];
                {
                    const float4* rp = (const float4*)(wb + (size_t)g * D_);
                    if (USE_H) {
                        m[0] = nt_load4(rp + q * 2);
                        m[1] = nt_load4(rp + q * 2 + 1);
                        m[2] = nt_load4(rp + q * 2 + 32);
                        m[3] = nt_load4(rp + q * 2 + 33);
                    } else {
                        m[0] = rp[q * 2];     m[1] = rp[q * 2 + 1];
                        m[2] = rp[q * 2 + 32]; m[3] = rp[q * 2 + 33];
                    }
                }
                for (int step = 0; step < NSTEPS; step++) {
                    const int pr = ((step + 1 < NSTEPS) ? step + 1 : step) * 4 + g;
                    const float4* rpn = (const float4*)(wb + (size_t)pr * D_);
                    float4 n0, n1, n2, n3;
                    if (USE_H) {
                        n0 = nt_load4(rpn + q * 2);
                        n1 = nt_load4(rpn + q * 2 + 1);
                        n2 = nt_load4(rpn + q * 2 + 32);
                        n3 = nt_load4(rpn + q * 2 + 33);
                    } else {
                        n0 = rpn[q * 2];     n1 = rpn[q * 2 + 1];
                        n2 = rpn[q * 2 + 32]; n3 = rpn[q * 2 + 33];
                    }
                    if (USE_H && t == 0) {
                        const int r = step * 4 + g;
                        __half* hp = mh + (wrowbase + r) * D_;
                        #pragma unroll
                        for (int jj = 0; jj < 2; jj++) {
                            union { uint4 u4; __half2 h2[4]; } pk;
                            pk.h2[0] = __floats2half2_rn(m[jj*2].x,   m[jj*2].y);
                            pk.h2[1] = __floats2half2_rn(m[jj*2].z,   m[jj*2].w);
                            pk.h2[2] = __floats2half2_rn(m[jj*2+1].x, m[jj*2+1].y);
                            pk.h2[3] = __floats2half2_rn(m[jj*2+1].z, m[jj*2+1].w);
                            *(uint4*)(hp + q * 8 + 128 * jj) = pk.u4;
                        }
                    }
                    FAST_SCORE_UPDATE()
                    m[0] = n0; m[1] = n1; m[2] = n2; m[3] = n3;
                }
            }
        } else {
            // ============ SLOW PATH (general P): s = 0.5 m.v - Cn =========
            if (USE_H && t > 0) {
                for (int step = 0; step < NSTEPS; step++) {
                    const int r = step * 4 + g;
                    const __half* rp = mh + (wrowbase + r) * D_;
                    const float4 r0 = ((const float4*)rp)[q];
                    const float4 r1 = ((const float4*)rp)[q + 16];
                    float4 m[4];
                    cvt_h8(r0, r1, m);
                    const float cv = Cn[wrowbase + r];
                    SLOW_SCORE_UPDATE(cv)
                }
            } else {
                for (int step = 0; step < NSTEPS; step++) {
                    const int r = step * 4 + g;
                    const float* rp = means + (wrowbase + r) * D_;
                    float4 m[4];
                    #pragma unroll
                    for (int jj = 0; jj < 2; jj++)
                        #pragma unroll
                        for (int h = 0; h < 2; h++)
                            m[jj * 2 + h] = ((const float4*)rp)[q * 2 + 32 * jj + h];
                    if (USE_H && t == 0) {
                        __half* hp = mh + (wrowbase + r) * D_;
                        #pragma unroll
                        for (int jj = 0; jj < 2; jj++) {
                            union { uint4 u4; __half2 h2[4]; } pk;
                            pk.h2[0] = __floats2half2_rn(m[jj*2].x,   m[jj*2].y);
                            pk.h2[1] = __floats2half2_rn(m[jj*2].z,   m[jj*2].w);
                            pk.h2[2] = __floats2half2_rn(m[jj*2+1].x, m[jj*2+1].y);
                            pk.h2[3] = __floats2half2_rn(m[jj*2+1].z, m[jj*2+1].w);
                            *(uint4*)(hp + q * 8 + 128 * jj) = pk.u4;
                        }
                    }
                    const float cv = Cn[wrowbase + r];
                    SLOW_SCORE_UPDATE(cv)
                }
            }
        }

        // ---- epilogue: combine 4 lane-groups (xor 16/32), then 4 waves ----
        float Mw = runM;
        Mw = fmaxf(Mw, __shfl_xor(Mw, 16, 64));
        Mw = fmaxf(Mw, __shfl_xor(Mw, 32, 64));
        const float aw = __expf(runM - Mw);
        float Sa = runS * aw;
        Sa += __shfl_xor(Sa, 16, 64);
        Sa += __shfl_xor(Sa, 32, 64);
        #pragma unroll
        for (int j = 0; j < 4; j++) {
            tacc[j].x *= aw; tacc[j].y *= aw; tacc[j].z *= aw; tacc[j].w *= aw;
            tacc[j].x += __shfl_xor(tacc[j].x, 16, 64);
            tacc[j].y += __shfl_xor(tacc[j].y, 16, 64);
            tacc[j].z += __shfl_xor(tacc[j].z, 16, 64);
            tacc[j].w += __shfl_xor(tacc[j].w, 16, 64);
            tacc[j].x += __shfl_xor(tacc[j].x, 32, 64);
            tacc[j].y += __shfl_xor(tacc[j].y, 32, 64);
            tacc[j].z += __shfl_xor(tacc[j].z, 32, 64);
            tacc[j].w += __shfl_xor(tacc[j].w, 32, 64);
        }
        if (lane < 16) {
            #pragma unroll
            for (int j = 0; j < 4; j++)
                ((float4*)shbuf[wave])[q * 2 + 32 * (j >> 1) + (j & 1)] = tacc[j];
        }
        if (lane == 0) { wM[wave] = Mw; wS[wave] = Sa; }
        __syncthreads();
        const float Mb = fmaxf(fmaxf(wM[0], wM[1]), fmaxf(wM[2], wM[3]));
        const float a0 = __expf(wM[0] - Mb), a1 = __expf(wM[1] - Mb),
                    a2 = __expf(wM[2] - Mb), a3 = __expf(wM[3] - Mb);
        const float Tc = a0 * shbuf[0][tid] + a1 * shbuf[1][tid] +
                         a2 * shbuf[2][tid] + a3 * shbuf[3][tid];
        const int buf = t & 1;
        pT[((size_t)buf * GRID + gid) * D_ + tid] = Tc;
        if (tid == 0)
            pS[buf * GRID + gid] = make_float2(
                Mb, a0 * wS[0] + a1 * wS[1] + a2 * wS[2] + a3 * wS[3]);

        grid.sync();

        // ---- combine PARTS_ partials for my bb (redundant per part) ----
        float Mg = -INFINITY;
        float2 stl[PARTS_];
        #pragma unroll
        for (int pI = 0; pI < PARTS_; pI++) {
            stl[pI] = pS[buf * GRID + bb * PARTS_ + pI];
            Mg = fmaxf(Mg, stl[pI].x);
        }
        float Sg = 0.f, accg = 0.f;
        #pragma unroll
        for (int pI = 0; pI < PARTS_; pI++) {
            const float a = __expf(stl[pI].x - Mg);
            Sg += a * stl[pI].y;
            accg += a * pT[((size_t)buf * GRID + bb * PARTS_ + pI) * D_ + tid];
        }
        const float zv = accg / Sg;
        if (t == 9) {
            if (part == 0) out[bb * D_ + tid] = zv;
        } else {
            if (!flg) {
                vsh[tid] = 2.f * zv;
            } else {
                zsh[tid] = zv;
                __syncthreads();
                float vv = 0.f;
                for (int e = 0; e < D_; e++)
                    vv += (P[tid * D_ + e] + P[e * D_ + tid]) * zsh[e];
                vsh[tid] = vv;
            }
            __syncthreads();
        }
    }
}

// ===========================================================================
// Fallback multi-kernel path (round-4, proven) — used if workspace or
// cooperative occupancy is insufficient.
// ===========================================================================
__global__ __launch_bounds__(256) void vcalc_kernel(const float* __restrict__ P,
                                                    const float* __restrict__ z,
                                                    const int* __restrict__ flag,
                                                    float* __restrict__ v) {
    __shared__ float zsh[D_];
    const int b = blockIdx.x, d = threadIdx.x;
    const float zd = z[b * D_ + d];
    if (*flag == 0) {
        v[b * D_ + d] = 2.0f * zd;
        return;
    }
    zsh[d] = zd;
    __syncthreads();
    float acc = 0.f;
    for (int e = 0; e < D_; e++)
        acc += (P[d * D_ + e] + P[e * D_ + d]) * zsh[e];
    v[b * D_ + d] = acc;
}

template <bool WRITE_H>
__global__ __launch_bounds__(256) void fused_f32_kernel(const float* __restrict__ means,
                                                        const float* __restrict__ v,
                                                        const float* __restrict__ P,
                                                        const int* __restrict__ flag,
                                                        __half* __restrict__ mh,
                                                        float* __restrict__ Tbuf,
                                                        float2* __restrict__ stats) {
    const int b = blockIdx.y, chunk = blockIdx.x;
    const int tid = threadIdx.x, wave = tid >> 6, lane = tid & 63;
    const int q = lane & 15, g = lane >> 4;
    __shared__ __align__(16) float vsh[D_];
    __shared__ __align__(16) float shbuf[4][D_];
    __shared__ __align__(16) float srows[4][4][D_];
    __shared__ float wM[4], wS[4];
    vsh[tid] = v[b * D_ + tid];
    __syncthreads();
    float4 vr[4];
    #pragma unroll
    for (int jj = 0; jj < 2; jj++)
        #pragma unroll
        for (int h = 0; h < 2; h++)
            vr[jj * 2 + h] = ((const float4*)vsh)[q * 2 + 32 * jj + h];
    const int flg = *flag;

    float runM = -INFINITY, runS = 0.f;
    float4 tacc[4];
    #pragma unroll
    for (int j = 0; j < 4; j++) tacc[j] = make_float4(0.f, 0.f, 0.f, 0.f);

    const size_t rowbase = (size_t)b * N_ + (size_t)chunk * NPB + (size_t)wave * NPW;

    for (int step = 0; step < NSTEP; step++) {
        const int r = step * 4 + g;
        const float* rp = means + (rowbase + r) * D_;
        float4 m[4];
        #pragma unroll
        for (int jj = 0; jj < 2; jj++)
            #pragma unroll
            for (int h = 0; h < 2; h++)
                m[jj * 2 + h] = ((const float4*)rp)[q * 2 + 32 * jj + h];
        if (WRITE_H) {
            __half* hp = mh + (rowbase + r) * D_;
            #pragma unroll
            for (int jj = 0; jj < 2; jj++) {
                union { uint4 u4; __half2 h2[4]; } pk;
                pk.h2[0] = __floats2half2_rn(m[jj*2].x,   m[jj*2].y);
                pk.h2[1] = __floats2half2_rn(m[jj*2].z,   m[jj*2].w);
                pk.h2[2] = __floats2half2_rn(m[jj*2+1].x, m[jj*2+1].y);
                pk.h2[3] = __floats2half2_rn(m[jj*2+1].z, m[jj*2+1].w);
                *(uint4*)(hp + q * 8 + 128 * jj) = pk.u4;
            }
        }
        SCORE_AND_UPDATE()
    }

    float Mw = runM;
    Mw = fmaxf(Mw, __shfl_xor(Mw, 16, 64));
    Mw = fmaxf(Mw, __shfl_xor(Mw, 32, 64));
    const float aw = __expf(runM - Mw);
    float Sa = runS * aw;
    Sa += __shfl_xor(Sa, 16, 64);
    Sa += __shfl_xor(Sa, 32, 64);
    #pragma unroll
    for (int j = 0; j < 4; j++) {
        tacc[j].x *= aw; tacc[j].y *= aw; tacc[j].z *= aw; tacc[j].w *= aw;
        tacc[j].x += __shfl_xor(tacc[j].x, 16, 64);
        tacc[j].y += __shfl_xor(tacc[j].y, 16, 64);
        tacc[j].z += __shfl_xor(tacc[j].z, 16, 64);
        tacc[j].w += __shfl_xor(tacc[j].w, 16, 64);
        tacc[j].x += __shfl_xor(tacc[j].x, 32, 64);
        tacc[j].y += __shfl_xor(tacc[j].y, 32, 64);
        tacc[j].z += __shfl_xor(tacc[j].z, 32, 64);
        tacc[j].w += __shfl_xor(tacc[j].w, 32, 64);
    }
    if (lane < 16) {
        #pragma unroll
        for (int j = 0; j < 4; j++)
            ((float4*)shbuf[wave])[q * 2 + 32 * (j >> 1) + (j & 1)] = tacc[j];
    }
    if (lane == 0) { wM[wave] = Mw; wS[wave] = Sa; }
    __syncthreads();
    const float Mb = fmaxf(fmaxf(wM[0], wM[1]), fmaxf(wM[2], wM[3]));
    const float a0 = __expf(wM[0] - Mb), a1 = __expf(wM[1] - Mb),
                a2 = __expf(wM[2] - Mb), a3 = __expf(wM[3] - Mb);
    const float Tc = a0 * shbuf[0][tid] + a1 * shbuf[1][tid] +
                     a2 * shbuf[2][tid] + a3 * shbuf[3][tid];
    Tbuf[((size_t)(b * NCH + chunk)) * D_ + tid] = Tc;
    if (tid == 0)
        stats[b * NCH + chunk] = make_float2(
            Mb, a0 * wS[0] + a1 * wS[1] + a2 * wS[2] + a3 * wS[3]);
}

__global__ __launch_bounds__(256) void fused_f16_kernel(const __half* __restrict__ mh,
                                                        const float* __restrict__ v,
                                                        const float* __restrict__ P,
                                                        const int* __restrict__ flag,
                                                        float* __restrict__ Tbuf,
                                                        float2* __restrict__ stats) {
    const int b = blockIdx.y, chunk = blockIdx.x;
    const int tid = threadIdx.x, wave = tid >> 6, lane = tid & 63;
    const int q = lane & 15, g = lane >> 4;
    __shared__ __align__(16) float vsh[D_];
    __shared__ __align__(16) float shbuf[4][D_];
    __shared__ __align__(16) float srows[4][4][D_];
    __shared__ float wM[4], wS[4];
    vsh[tid] = v[b * D_ + tid];
    __syncthreads();
    float4 vr[4];
    #pragma unroll
    for (int jj = 0; jj < 2; jj++)
        #pragma unroll
        for (int h = 0; h < 2; h++)
            vr[jj * 2 + h] = ((const float4*)vsh)[q * 2 + 32 * jj + h];
    const int flg = *flag;

    float runM = -INFINITY, runS = 0.f;
    float4 tacc[4];
    #pragma unroll
    for (int j = 0; j < 4; j++) tacc[j] = make_float4(0.f, 0.f, 0.f, 0.f);

    const size_t rowbase = (size_t)b * N_ + (size_t)chunk * NPB + (size_t)wave * NPW;

    for (int step = 0; step < NSTEP; step++) {
        const int r = step * 4 + g;
        const __half* rp = mh + (rowbase + r) * D_;
        float4 m[4];
        #pragma unroll
        for (int jj = 0; jj < 2; jj++) {
            float4 raw = ((const float4*)rp)[q + 16 * jj];
            const __half2* hp2 = (const __half2*)&raw;
            const float2 f0 = __half22float2(hp2[0]);
            const float2 f1 = __half22float2(hp2[1]);
            const float2 f2 = __half22float2(hp2[2]);
            const float2 f3 = __half22float2(hp2[3]);
            m[jj * 2 + 0] = make_float4(f0.x, f0.y, f1.x, f1.y);
            m[jj * 2 + 1] = make_float4(f2.x, f2.y, f3.x, f3.y);
        }
        SCORE_AND_UPDATE()
    }

    float Mw = runM;
    Mw = fmaxf(Mw, __shfl_xor(Mw, 16, 64));
    Mw = fmaxf(Mw, __shfl_xor(Mw, 32, 64));
    const float aw = __expf(runM - Mw);
    float Sa = runS * aw;
    Sa += __shfl_xor(Sa, 16, 64);
    Sa += __shfl_xor(Sa, 32, 64);
    #pragma unroll
    for (int j = 0; j < 4; j++) {
        tacc[j].x *= aw; tacc[j].y *= aw; tacc[j].z *= aw; tacc[j].w *= aw;
        tacc[j].x += __shfl_xor(tacc[j].x, 16, 64);
        tacc[j].y += __shfl_xor(tacc[j].y, 16, 64);
        tacc[j].z += __shfl_xor(tacc[j].z, 16, 64);
        tacc[j].w += __shfl_xor(tacc[j].w, 16, 64);
        tacc[j].x += __shfl_xor(tacc[j].x, 32, 64);
        tacc[j].y += __shfl_xor(tacc[j].y, 32, 64);
        tacc[j].z += __shfl_xor(tacc[j].z, 32, 64);
        tacc[j].w += __shfl_xor(tacc[j].w, 32, 64);
    }
    if (lane < 16) {
        #pragma unroll
        for (int j = 0; j < 4; j++)
            ((float4*)shbuf[wave])[q * 2 + 32 * (j >> 1) + (j & 1)] = tacc[j];
    }
    if (lane == 0) { wM[wave] = Mw; wS[wave] = Sa; }
    __syncthreads();
    const float Mb = fmaxf(fmaxf(wM[0], wM[1]), fmaxf(wM[2], wM[3]));
    const float a0 = __expf(wM[0] - Mb), a1 = __expf(wM[1] - Mb),
                a2 = __expf(wM[2] - Mb), a3 = __expf(wM[3] - Mb);
    const float Tc = a0 * shbuf[0][tid] + a1 * shbuf[1][tid] +
                     a2 * shbuf[2][tid] + a3 * shbuf[3][tid];
    Tbuf[((size_t)(b * NCH + chunk)) * D_ + tid] = Tc;
    if (tid == 0)
        stats[b * NCH + chunk] = make_float2(
            Mb, a0 * wS[0] + a1 * wS[1] + a2 * wS[2] + a3 * wS[3]);
}

__global__ __launch_bounds__(256) void combine_kernel(const float* __restrict__ Tbuf,
                                                      const float2* __restrict__ stats,
                                                      const float* __restrict__ P,
                                                      const int* __restrict__ flag,
                                                      float* __restrict__ v,
                                                      float* __restrict__ out) {
    const int b = blockIdx.x, d = threadIdx.x;
    __shared__ float Msh[NCH], Ssh[NCH];
    __shared__ float zsh[D_];
    if (d < NCH) {
        const float2 st = stats[b * NCH + d];
        Msh[d] = st.x; Ssh[d] = st.y;
    }
    __syncthreads();
    float M = -INFINITY;
    for (int c = 0; c < NCH; c++) M = fmaxf(M, Msh[c]);
    float S = 0.f, acc = 0.f;
    for (int c = 0; c < NCH; c++) {
        const float a = __expf(Msh[c] - M);
        S += a * Ssh[c];
        acc += a * Tbuf[((size_t)(b * NCH + c)) * D_ + d];
    }
    const float z = acc / S;
    if (out) out[b * D_ + d] = z;
    if (*flag == 0) {
        v[b * D_ + d] = 2.0f * z;
        return;
    }
    zsh[d] = z;
    __syncthreads();
    float vv = 0.f;
    for (int e = 0; e < D_; e++)
        vv += (P[d * D_ + e] + P[e * D_ + d]) * zsh[e];
    v[b * D_ + d] = vv;
}

extern "C" void kernel_launch(void* const* d_in, const int* in_sizes, int n_in,
                              void* d_out, int out_size, void* d_ws, size_t ws_size,
                              hipStream_t stream) {
    // inputs: 0=x (unused), 1=z, 2=means, 3=precision, 4=iterations(=10)
    const float* z0    = (const float*)d_in[1];
    const float* means = (const float*)d_in[2];
    const float* P     = (const float*)d_in[3];
    float* out = (float*)d_out;

    char* ws = (char*)d_ws;
    size_t off = 0;
    int*    flag  = (int*)ws;                     off = 256;
    float*  v     = (float*)(ws + off);           off += (size_t)B_ * D_ * 4;
    float*  Tbuf  = (float*)(ws + off);           off += (size_t)B_ * NCH * D_ * 4;
    float2* stats = (float2*)(ws + off);          off += (size_t)B_ * NCH * 8;
    off = (off + 255) & ~(size_t)255;
    float*  pT    = (float*)(ws + off);           off += 2ull * 1024 * D_ * 4;
    float2* pS    = (float2*)(ws + off);          off += 2ull * 1024 * 8;
    off = (off + 255) & ~(size_t)255;
    float*  Cn    = (float*)(ws + off);           off += (size_t)B_ * N_ * 4;
    off = (off + 255) & ~(size_t)255;
    __half* mh    = (__half*)(ws + off);
    const size_t coop_need  = off;                               // ~7.4 MiB
    const size_t full_need  = off + (size_t)B_ * N_ * D_ * 2;    // + 128 MiB
    const bool use_h = (ws_size >= full_need);
    const bool ws_ok = (ws_size >= coop_need);

    flag_kernel<<<dim3(1), dim3(256), 0, stream>>>(P, flag);

    // ---- cooperative persistent path (preferred) ----
    if (ws_ok) {
        // Cn precompute (no-op when P == I)
        cn_kernel<<<dim3(B_ * N_ / CNR), dim3(256), 0, stream>>>(means, P, flag, Cn);

        void* args[] = {(void*)&means, (void*)&z0, (void*)&P, (void*)&flag,
                        (void*)&Cn, (void*)&mh, (void*)&pT, (void*)&pS, (void*)&out};
        int nb = 0;
        if (use_h) {
            if (hipOccupancyMaxActiveBlocksPerMultiprocessor(
                    &nb, persistent_kernel<true, 16>, 256, 0) == hipSuccess && nb >= 4) {
                if (hipLaunchCooperativeKernel(persistent_kernel<true, 16>,
                        dim3(1024), dim3(256), args, 0, stream) == hipSuccess)
                    return;
            }
            nb = 0;
            if (hipOccupancyMaxActiveBlocksPerMultiprocessor(
                    &nb, persistent_kernel<true, 8>, 256, 0) == hipSuccess && nb >= 2) {
                if (hipLaunchCooperativeKernel(persistent_kernel<true, 8>,
                        dim3(512), dim3(256), args, 0, stream) == hipSuccess)
                    return;
            }
        } else {
            if (hipOccupancyMaxActiveBlocksPerMultiprocessor(
                    &nb, persistent_kernel<false, 16>, 256, 0) == hipSuccess && nb >= 4) {
                if (hipLaunchCooperativeKernel(persistent_kernel<false, 16>,
                        dim3(1024), dim3(256), args, 0, stream) == hipSuccess)
                    return;
            }
            nb = 0;
            if (hipOccupancyMaxActiveBlocksPerMultiprocessor(
                    &nb, persistent_kernel<false, 8>, 256, 0) == hipSuccess && nb >= 2) {
                if (hipLaunchCooperativeKernel(persistent_kernel<false, 8>,
                        dim3(512), dim3(256), args, 0, stream) == hipSuccess)
                    return;
            }
        }
    }

    // ---- fallback multi-kernel path (round-4) ----
    vcalc_kernel<<<dim3(B_), dim3(256), 0, stream>>>(P, z0, flag, v);
    if (use_h) {
        fused_f32_kernel<true><<<dim3(NCH, B_), dim3(256), 0, stream>>>(
            means, v, P, flag, mh, Tbuf, stats);
        combine_kernel<<<dim3(B_), dim3(256), 0, stream>>>(Tbuf, stats, P, flag, v, nullptr);
        for (int t = 1; t < 10; t++) {
            fused_f16_kernel<<<dim3(NCH, B_), dim3(256), 0, stream>>>(
                mh, v, P, flag, Tbuf, stats);
            combine_kernel<<<dim3(B_), dim3(256), 0, stream>>>(Tbuf, stats, P, flag, v,
                                                               (t == 9) ? out : nullptr);
        }
    } else {
        for (int t = 0; t < 10; t++) {
            fused_f32_kernel<false><<<dim3(NCH, B_), dim3(256), 0, stream>>>(
                means, v, P, flag, nullptr, Tbuf, stats);
            combine_kernel<<<dim3(B_), dim3(256), 0, stream>>>(Tbuf, stats, P, flag, v,
                                                               (t == 9) ? out : nullptr);
        }
    }
}

// Round 4
// 739.079 us; speedup vs baseline: 1.9758x; 1.6279x over previous
//
#include <hip/hip_runtime.h>
#include <hip/hip_fp16.h>
#include <hip/hip_cooperative_groups.h>
#include <math.h>
#include <stdint.h>

namespace cg = cooperative_groups;

constexpr int B_ = 64;
constexpr int N_ = 4096;
constexpr int D_ = 256;
constexpr int NCH = 64;            // fallback path: chunks per batch row
constexpr int NPB = N_ / NCH;      // 64 rows per block
constexpr int NPW = NPB / 4;       // 16 rows per wave
constexpr int NSTEP = NPW / 4;     // fallback: 4 steps of 4 rows
constexpr int CNR = 16;            // rows per block in cn_kernel

// nontemporal float4 load (ext_vector to satisfy the builtin's type rules)
typedef float f4v __attribute__((ext_vector_type(4)));
__device__ __forceinline__ float4 nt_load4(const float4* p) {
    f4v v = __builtin_nontemporal_load((const f4v*)p);
    return make_float4(v.x, v.y, v.z, v.w);
}

// async global->LDS copy, 16 B per lane. HW dest = uniform base + lane*16.
__device__ __forceinline__ void gload_lds16(const void* g, void* l) {
    __builtin_amdgcn_global_load_lds(
        (const __attribute__((address_space(1))) void*)(uintptr_t)g,
        (__attribute__((address_space(3))) void*)(uint32_t)(uintptr_t)l,
        16, 0, 0);
}

template <int N>
__device__ __forceinline__ void wait_vmcnt() {
    asm volatile("s_waitcnt vmcnt(%0)" ::"n"(N) : "memory");
}

// unpack 8 halves (two float4-sized raw loads) into 4 float4
__device__ __forceinline__ void cvt_h8(const float4 r0, const float4 r1, float4 m[4]) {
    const __half2* h0 = (const __half2*)&r0;
    const float2 f0 = __half22float2(h0[0]);
    const float2 f1 = __half22float2(h0[1]);
    const float2 f2 = __half22float2(h0[2]);
    const float2 f3 = __half22float2(h0[3]);
    m[0] = make_float4(f0.x, f0.y, f1.x, f1.y);
    m[1] = make_float4(f2.x, f2.y, f3.x, f3.y);
    const __half2* h1 = (const __half2*)&r1;
    const float2 g0 = __half22float2(h1[0]);
    const float2 g1 = __half22float2(h1[1]);
    const float2 g2 = __half22float2(h1[2]);
    const float2 g3 = __half22float2(h1[3]);
    m[2] = make_float4(g0.x, g0.y, g1.x, g1.y);
    m[3] = make_float4(g2.x, g2.y, g3.x, g3.y);
}

// ---------------------------------------------------------------------------
// flag: is precision == I?  0 -> fast paths everywhere.
// ---------------------------------------------------------------------------
__global__ __launch_bounds__(256) void flag_kernel(const float* __restrict__ P,
                                                   int* __restrict__ flag) {
    __shared__ int sh[256];
    const int tid = threadIdx.x;
    int bad = 0;
    for (int i = tid; i < D_ * D_; i += 256) {
        const int r = i >> 8, c = i & 255;
        const float expect = (r == c) ? 1.0f : 0.0f;
        bad |= (P[i] != expect) ? 1 : 0;
    }
    sh[tid] = bad;
    __syncthreads();
    for (int s = 128; s > 0; s >>= 1) {
        if (tid < s) sh[tid] |= sh[tid + s];
        __syncthreads();
    }
    if (tid == 0) *flag = sh[0];
}

// ---------------------------------------------------------------------------
// Cn[row] = 0.5 * m_row^T P m_row  (iteration-invariant general-P correction).
// ---------------------------------------------------------------------------
__global__ __launch_bounds__(256) void cn_kernel(const float* __restrict__ means,
                                                 const float* __restrict__ P,
                                                 const int* __restrict__ flag,
                                                 float* __restrict__ Cn) {
    if (*flag == 0) return;
    const int row0 = blockIdx.x * CNR;
    const int d = threadIdx.x;
    __shared__ __align__(16) float msh[CNR][D_];
    __shared__ float red[CNR][4];
    #pragma unroll
    for (int i = 0; i < CNR; i++)
        msh[i][d] = means[(size_t)(row0 + i) * D_ + d];
    __syncthreads();
    float acc[CNR];
    #pragma unroll
    for (int r = 0; r < CNR; r++) acc[r] = 0.f;
    for (int e = 0; e < D_; e++) {
        const float pde = P[d * D_ + e];
        #pragma unroll
        for (int r = 0; r < CNR; r++) acc[r] = fmaf(pde, msh[r][e], acc[r]);
    }
    const int lane = d & 63, wv = d >> 6;
    #pragma unroll
    for (int r = 0; r < CNR; r++) {
        float pv = msh[r][d] * acc[r];
        for (int s = 1; s < 64; s <<= 1) pv += __shfl_xor(pv, s, 64);
        if (lane == 0) red[r][wv] = pv;
    }
    __syncthreads();
    if (d < CNR)
        Cn[row0 + d] = 0.5f * (red[d][0] + red[d][1] + red[d][2] + red[d][3]);
}

// ---------------------------------------------------------------------------
// Online-softmax building blocks (no LDS, no barriers).
// ---------------------------------------------------------------------------
#define REDUCE16(P)                                                            \
    P += __shfl_xor(P, 1, 64);                                                 \
    P += __shfl_xor(P, 2, 64);                                                 \
    P += __shfl_xor(P, 4, 64);                                                 \
    P += __shfl_xor(P, 8, 64);

#define ONLINE_UPDATE(SEXPR)                                                   \
    {                                                                          \
        const float s_ = (SEXPR);                                              \
        const float newM_ = fmaxf(runM, s_);                                   \
        const float sc_ = __expf(runM - newM_);                                \
        const float e_  = __expf(s_ - newM_);                                  \
        runS = fmaf(runS, sc_, e_);                                            \
        _Pragma("unroll")                                                      \
        for (int j = 0; j < 4; j++) {                                          \
            tacc[j].x = fmaf(tacc[j].x, sc_, e_ * m[j].x);                     \
            tacc[j].y = fmaf(tacc[j].y, sc_, e_ * m[j].y);                     \
            tacc[j].z = fmaf(tacc[j].z, sc_, e_ * m[j].z);                     \
            tacc[j].w = fmaf(tacc[j].w, sc_, e_ * m[j].w);                     \
        }                                                                      \
        runM = newM_;                                                          \
    }

// FAST (P == I): s = 0.5 * sum m*(v-m)
#define FAST_SCORE_UPDATE()                                                    \
    {                                                                          \
        float pa = 0.f, pb = 0.f, pc2 = 0.f, pd = 0.f;                         \
        _Pragma("unroll")                                                      \
        for (int j = 0; j < 4; j++) {                                          \
            pa  = fmaf(m[j].x, vr[j].x - m[j].x, pa);                          \
            pb  = fmaf(m[j].y, vr[j].y - m[j].y, pb);                          \
            pc2 = fmaf(m[j].z, vr[j].z - m[j].z, pc2);                         \
            pd  = fmaf(m[j].w, vr[j].w - m[j].w, pd);                          \
        }                                                                      \
        float p_ = (pa + pb) + (pc2 + pd);                                     \
        REDUCE16(p_)                                                           \
        ONLINE_UPDATE(0.5f * p_)                                               \
    }

// SLOW (general P): s = 0.5 * (m . v) - Cn[row]
#define SLOW_SCORE_UPDATE(CV)                                                  \
    {                                                                          \
        float pa = 0.f, pb = 0.f, pc2 = 0.f, pd = 0.f;                         \
        _Pragma("unroll")                                                      \
        for (int j = 0; j < 4; j++) {                                          \
            pa  = fmaf(m[j].x, vr[j].x, pa);                                   \
            pb  = fmaf(m[j].y, vr[j].y, pb);                                   \
            pc2 = fmaf(m[j].z, vr[j].z, pc2);                                  \
            pd  = fmaf(m[j].w, vr[j].w, pd);                                   \
        }                                                                      \
        float p_ = (pa + pb) + (pc2 + pd);                                     \
        REDUCE16(p_)                                                           \
        ONLINE_UPDATE(0.5f * p_ - (CV))                                        \
    }

// Fallback-path per-row score (uses srows LDS; only in fallback kernels).
#define SCORE_AND_UPDATE()                                                     \
    {                                                                          \
        float p_ = 0.f;                                                        \
        _Pragma("unroll")                                                      \
        for (int j = 0; j < 4; j++) {                                          \
            p_ += m[j].x * (vr[j].x - m[j].x);                                 \
            p_ += m[j].y * (vr[j].y - m[j].y);                                 \
            p_ += m[j].z * (vr[j].z - m[j].z);                                 \
            p_ += m[j].w * (vr[j].w - m[j].w);                                 \
        }                                                                      \
        p_ += __shfl_xor(p_, 1, 64);                                           \
        p_ += __shfl_xor(p_, 2, 64);                                           \
        p_ += __shfl_xor(p_, 4, 64);                                           \
        p_ += __shfl_xor(p_, 8, 64);                                           \
        float s_ = 0.5f * p_;                                                  \
        if (flg) {                                                             \
            __syncthreads();                                                   \
            _Pragma("unroll")                                                  \
            for (int jj = 0; jj < 2; jj++)                                     \
                _Pragma("unroll")                                              \
                for (int h = 0; h < 2; h++)                                    \
                    ((float4*)&srows[wave][g][0])[q * 2 + 32 * jj + h] =       \
                        m[jj * 2 + h];                                         \
            __syncthreads();                                                   \
            float dl = 0.f;                                                    \
            for (int k = 0; k < 16; k++) {                                     \
                const int d_ = q * 16 + k;                                     \
                const float md = srows[wave][g][d_];                           \
                float pm = 0.f;                                                \
                for (int e = 0; e < D_; e++)                                   \
                    pm += P[d_ * D_ + e] * srows[wave][g][e];                  \
                dl += md * (md - pm);                                          \
            }                                                                  \
            dl += __shfl_xor(dl, 1, 64);                                       \
            dl += __shfl_xor(dl, 2, 64);                                       \
            dl += __shfl_xor(dl, 4, 64);                                       \
            dl += __shfl_xor(dl, 8, 64);                                       \
            s_ += 0.5f * dl;                                                   \
        }                                                                      \
        const float newM_ = fmaxf(runM, s_);                                   \
        const float sc_ = __expf(runM - newM_);                                \
        const float e_  = __expf(s_ - newM_);                                  \
        runS = fmaf(runS, sc_, e_);                                            \
        _Pragma("unroll")                                                      \
        for (int j = 0; j < 4; j++) {                                          \
            tacc[j].x = fmaf(tacc[j].x, sc_, e_ * m[j].x);                     \
            tacc[j].y = fmaf(tacc[j].y, sc_, e_ * m[j].y);                     \
            tacc[j].z = fmaf(tacc[j].z, sc_, e_ * m[j].z);                     \
            tacc[j].w = fmaf(tacc[j].w, sc_, e_ * m[j].w);                     \
        }                                                                      \
        runM = newM_;                                                          \
    }

// ---------------------------------------------------------------------------
// Wave-private LDS ring staging (f16 iterations t>=1).
// Slot = 4 rows * 512B = 2048B. 2 gload_lds of 1KB per slot (lanes 0-31 =
// first row half... HW writes base + lane*16 linearly = row-major [4][512B]).
// Counted vmcnt, no __syncthreads in the loop -> loads stay in flight.
// ---------------------------------------------------------------------------
#define RSTAGE(SLOT, STEP)                                                     \
    {                                                                          \
        const __half* sp_ = wb + (size_t)(4 * (STEP) + (lane >> 5)) * D_       \
                            + (size_t)(lane & 31) * 8;                         \
        gload_lds16(sp_, myring + (SLOT) * 2048);                              \
        gload_lds16(sp_ + 2 * D_, myring + (SLOT) * 2048 + 1024);              \
    }

#define RBODY(SLOT, STEP, RSTEP, DO_REFILL, WAITN)                             \
    {                                                                          \
        wait_vmcnt<WAITN>();                                                   \
        const float4* sf_ = (const float4*)(myring + (SLOT) * 2048);           \
        const float4 r0 = sf_[g * 32 + q];                                     \
        const float4 r1 = sf_[g * 32 + 16 + q];                                \
        asm volatile("" ::: "memory");                                         \
        if (DO_REFILL) RSTAGE(SLOT, RSTEP)                                     \
        float4 m[4];                                                           \
        cvt_h8(r0, r1, m);                                                     \
        FAST_SCORE_UPDATE()                                                    \
    }

// ---------------------------------------------------------------------------
// Persistent cooperative kernel: all 10 iterations in one launch.
// LDS: 16K ring + ~6.2K = ~22.2KB -> 2 blocks/CU. PARTS_=8 -> 512 blocks
// co-resident. No launch_bounds reg cap: ring needs no pipeline VGPRs.
// ---------------------------------------------------------------------------
template <bool USE_H, int PARTS_>
__global__ __launch_bounds__(256) void persistent_kernel(
        const float* __restrict__ means, const float* __restrict__ z0,
        const float* __restrict__ P, const int* __restrict__ flag,
        const float* __restrict__ Cn, __half* __restrict__ mh,
        float* __restrict__ pT, float2* __restrict__ pS,
        float* __restrict__ out) {
    constexpr int GRID = 64 * PARTS_;
    constexpr int RPB = N_ / PARTS_;   // rows per block
    constexpr int RPW = RPB / 4;       // rows per wave
    constexpr int NSTEPS = RPW / 4;    // 4 rows (one per 16-lane group) per step
    static_assert(NSTEPS % 2 == 0, "ring needs even NSTEPS");
    cg::grid_group grid = cg::this_grid();

    const int gid = blockIdx.x, bb = gid / PARTS_, part = gid % PARTS_;
    const int tid = threadIdx.x, wave = tid >> 6, lane = tid & 63;
    const int q = lane & 15, g = lane >> 4;

    __shared__ __align__(16) char ringbuf[4][2][2048];   // wave-private rings
    __shared__ __align__(16) float vsh[D_];
    __shared__ __align__(16) float shbuf[4][D_];
    __shared__ __align__(16) float zsh[D_];
    __shared__ float wM[4], wS[4];

    const int flg = *flag;
    char* const myring = &ringbuf[wave][0][0];

    // v0 = (P+P^T) z0  (fast path 2*z0)
    {
        const float zd = z0[bb * D_ + tid];
        if (!flg) {
            vsh[tid] = 2.f * zd;
        } else {
            zsh[tid] = zd;
            __syncthreads();
            float vv = 0.f;
            for (int e = 0; e < D_; e++)
                vv += (P[tid * D_ + e] + P[e * D_ + tid]) * zsh[e];
            vsh[tid] = vv;
        }
        __syncthreads();
    }

    const size_t wrowbase = (size_t)bb * N_ + (size_t)part * RPB + (size_t)wave * RPW;

    for (int t = 0; t < 10; t++) {
        float4 vr[4];   // vr[jj*2+h] covers d = q*8 + 128*jj + 4*h
        #pragma unroll
        for (int jj = 0; jj < 2; jj++)
            #pragma unroll
            for (int h = 0; h < 2; h++)
                vr[jj * 2 + h] = ((const float4*)vsh)[q * 2 + 32 * jj + h];

        float runM = -INFINITY, runS = 0.f;
        float4 tacc[4];
        #pragma unroll
        for (int j = 0; j < 4; j++) tacc[j] = make_float4(0.f, 0.f, 0.f, 0.f);

        if (!flg) {
            // ================= FAST PATH (P == I) ========================
            if (USE_H && t > 0) {
                // f16 via wave-private gload_lds ring, counted vmcnt.
                const __half* wb = mh + wrowbase * D_;
                RSTAGE(0, 0)
                RSTAGE(1, 1)
                for (int i = 0; i < NSTEPS - 2; i += 2) {
                    RBODY(0, i, i + 2, true, 2)
                    RBODY(1, i + 1, i + 3, true, 2)
                }
                RBODY(0, NSTEPS - 2, 0, false, 2)
                RBODY(1, NSTEPS - 1, 0, false, 0)
            } else {
                // f32 (t==0 with f16 write-out, or !USE_H every t), depth-1.
                const float* wb = means + wrowbase * D_;
                float4 m[4];
                {
                    const float4* rp = (const float4*)(wb + (size_t)g * D_);
                    if (USE_H) {
                        m[0] = nt_load4(rp + q * 2);
                        m[1] = nt_load4(rp + q * 2 + 1);
                        m[2] = nt_load4(rp + q * 2 + 32);
                        m[3] = nt_load4(rp + q * 2 + 33);
                    } else {
                        m[0] = rp[q * 2];     m[1] = rp[q * 2 + 1];
                        m[2] = rp[q * 2 + 32]; m[3] = rp[q * 2 + 33];
                    }
                }
                for (int step = 0; step < NSTEPS; step++) {
                    const int pr = ((step + 1 < NSTEPS) ? step + 1 : step) * 4 + g;
                    const float4* rpn = (const float4*)(wb + (size_t)pr * D_);
                    float4 n0, n1, n2, n3;
                    if (USE_H) {
                        n0 = nt_load4(rpn + q * 2);
                        n1 = nt_load4(rpn + q * 2 + 1);
                        n2 = nt_load4(rpn + q * 2 + 32);
                        n3 = nt_load4(rpn + q * 2 + 33);
                    } else {
                        n0 = rpn[q * 2];     n1 = rpn[q * 2 + 1];
                        n2 = rpn[q * 2 + 32]; n3 = rpn[q * 2 + 33];
                    }
                    if (USE_H && t == 0) {
                        const int r = step * 4 + g;
                        __half* hp = mh + (wrowbase + r) * D_;
                        #pragma unroll
                        for (int jj = 0; jj < 2; jj++) {
                            union { uint4 u4; __half2 h2[4]; } pk;
                            pk.h2[0] = __floats2half2_rn(m[jj*2].x,   m[jj*2].y);
                            pk.h2[1] = __floats2half2_rn(m[jj*2].z,   m[jj*2].w);
                            pk.h2[2] = __floats2half2_rn(m[jj*2+1].x, m[jj*2+1].y);
                            pk.h2[3] = __floats2half2_rn(m[jj*2+1].z, m[jj*2+1].w);
                            *(uint4*)(hp + q * 8 + 128 * jj) = pk.u4;
                        }
                    }
                    FAST_SCORE_UPDATE()
                    m[0] = n0; m[1] = n1; m[2] = n2; m[3] = n3;
                }
            }
        } else {
            // ============ SLOW PATH (general P): s = 0.5 m.v - Cn =========
            if (USE_H && t > 0) {
                for (int step = 0; step < NSTEPS; step++) {
                    const int r = step * 4 + g;
                    const __half* rp = mh + (wrowbase + r) * D_;
                    const float4 r0 = ((const float4*)rp)[q];
                    const float4 r1 = ((const float4*)rp)[q + 16];
                    float4 m[4];
                    cvt_h8(r0, r1, m);
                    const float cv = Cn[wrowbase + r];
                    SLOW_SCORE_UPDATE(cv)
                }
            } else {
                for (int step = 0; step < NSTEPS; step++) {
                    const int r = step * 4 + g;
                    const float* rp = means + (wrowbase + r) * D_;
                    float4 m[4];
                    #pragma unroll
                    for (int jj = 0; jj < 2; jj++)
                        #pragma unroll
                        for (int h = 0; h < 2; h++)
                            m[jj * 2 + h] = ((const float4*)rp)[q * 2 + 32 * jj + h];
                    if (USE_H && t == 0) {
                        __half* hp = mh + (wrowbase + r) * D_;
                        #pragma unroll
                        for (int jj = 0; jj < 2; jj++) {
                            union { uint4 u4; __half2 h2[4]; } pk;
                            pk.h2[0] = __floats2half2_rn(m[jj*2].x,   m[jj*2].y);
                            pk.h2[1] = __floats2half2_rn(m[jj*2].z,   m[jj*2].w);
                            pk.h2[2] = __floats2half2_rn(m[jj*2+1].x, m[jj*2+1].y);
                            pk.h2[3] = __floats2half2_rn(m[jj*2+1].z, m[jj*2+1].w);
                            *(uint4*)(hp + q * 8 + 128 * jj) = pk.u4;
                        }
                    }
                    const float cv = Cn[wrowbase + r];
                    SLOW_SCORE_UPDATE(cv)
                }
            }
        }

        // ---- epilogue: combine 4 lane-groups (xor 16/32), then 4 waves ----
        float Mw = runM;
        Mw = fmaxf(Mw, __shfl_xor(Mw, 16, 64));
        Mw = fmaxf(Mw, __shfl_xor(Mw, 32, 64));
        const float aw = __expf(runM - Mw);
        float Sa = runS * aw;
        Sa += __shfl_xor(Sa, 16, 64);
        Sa += __shfl_xor(Sa, 32, 64);
        #pragma unroll
        for (int j = 0; j < 4; j++) {
            tacc[j].x *= aw; tacc[j].y *= aw; tacc[j].z *= aw; tacc[j].w *= aw;
            tacc[j].x += __shfl_xor(tacc[j].x, 16, 64);
            tacc[j].y += __shfl_xor(tacc[j].y, 16, 64);
            tacc[j].z += __shfl_xor(tacc[j].z, 16, 64);
            tacc[j].w += __shfl_xor(tacc[j].w, 16, 64);
            tacc[j].x += __shfl_xor(tacc[j].x, 32, 64);
            tacc[j].y += __shfl_xor(tacc[j].y, 32, 64);
            tacc[j].z += __shfl_xor(tacc[j].z, 32, 64);
            tacc[j].w += __shfl_xor(tacc[j].w, 32, 64);
        }
        if (lane < 16) {
            #pragma unroll
            for (int j = 0; j < 4; j++)
                ((float4*)shbuf[wave])[q * 2 + 32 * (j >> 1) + (j & 1)] = tacc[j];
        }
        if (lane == 0) { wM[wave] = Mw; wS[wave] = Sa; }
        __syncthreads();
        const float Mb = fmaxf(fmaxf(wM[0], wM[1]), fmaxf(wM[2], wM[3]));
        const float a0 = __expf(wM[0] - Mb), a1 = __expf(wM[1] - Mb),
                    a2 = __expf(wM[2] - Mb), a3 = __expf(wM[3] - Mb);
        const float Tc = a0 * shbuf[0][tid] + a1 * shbuf[1][tid] +
                         a2 * shbuf[2][tid] + a3 * shbuf[3][tid];
        const int buf = t & 1;
        pT[((size_t)buf * GRID + gid) * D_ + tid] = Tc;
        if (tid == 0)
            pS[buf * GRID + gid] = make_float2(
                Mb, a0 * wS[0] + a1 * wS[1] + a2 * wS[2] + a3 * wS[3]);

        grid.sync();

        // ---- combine PARTS_ partials for my bb (redundant per part) ----
        float Mg = -INFINITY;
        float2 stl[PARTS_];
        #pragma unroll
        for (int pI = 0; pI < PARTS_; pI++) {
            stl[pI] = pS[buf * GRID + bb * PARTS_ + pI];
            Mg = fmaxf(Mg, stl[pI].x);
        }
        float Sg = 0.f, accg = 0.f;
        #pragma unroll
        for (int pI = 0; pI < PARTS_; pI++) {
            const float a = __expf(stl[pI].x - Mg);
            Sg += a * stl[pI].y;
            accg += a * pT[((size_t)buf * GRID + bb * PARTS_ + pI) * D_ + tid];
        }
        const float zv = accg / Sg;
        if (t == 9) {
            if (part == 0) out[bb * D_ + tid] = zv;
        } else {
            if (!flg) {
                vsh[tid] = 2.f * zv;
            } else {
                zsh[tid] = zv;
                __syncthreads();
                float vv = 0.f;
                for (int e = 0; e < D_; e++)
                    vv += (P[tid * D_ + e] + P[e * D_ + tid]) * zsh[e];
                vsh[tid] = vv;
            }
            __syncthreads();
        }
    }
}

// ===========================================================================
// Fallback multi-kernel path (round-4, proven).
// ===========================================================================
__global__ __launch_bounds__(256) void vcalc_kernel(const float* __restrict__ P,
                                                    const float* __restrict__ z,
                                                    const int* __restrict__ flag,
                                                    float* __restrict__ v) {
    __shared__ float zsh[D_];
    const int b = blockIdx.x, d = threadIdx.x;
    const float zd = z[b * D_ + d];
    if (*flag == 0) {
        v[b * D_ + d] = 2.0f * zd;
        return;
    }
    zsh[d] = zd;
    __syncthreads();
    float acc = 0.f;
    for (int e = 0; e < D_; e++)
        acc += (P[d * D_ + e] + P[e * D_ + d]) * zsh[e];
    v[b * D_ + d] = acc;
}

template <bool WRITE_H>
__global__ __launch_bounds__(256) void fused_f32_kernel(const float* __restrict__ means,
                                                        const float* __restrict__ v,
                                                        const float* __restrict__ P,
                                                        const int* __restrict__ flag,
                                                        __half* __restrict__ mh,
                                                        float* __restrict__ Tbuf,
                                                        float2* __restrict__ stats) {
    const int b = blockIdx.y, chunk = blockIdx.x;
    const int tid = threadIdx.x, wave = tid >> 6, lane = tid & 63;
    const int q = lane & 15, g = lane >> 4;
    __shared__ __align__(16) float vsh[D_];
    __shared__ __align__(16) float shbuf[4][D_];
    __shared__ __align__(16) float srows[4][4][D_];
    __shared__ float wM[4], wS[4];
    vsh[tid] = v[b * D_ + tid];
    __syncthreads();
    float4 vr[4];
    #pragma unroll
    for (int jj = 0; jj < 2; jj++)
        #pragma unroll
        for (int h = 0; h < 2; h++)
            vr[jj * 2 + h] = ((const float4*)vsh)[q * 2 + 32 * jj + h];
    const int flg = *flag;

    float runM = -INFINITY, runS = 0.f;
    float4 tacc[4];
    #pragma unroll
    for (int j = 0; j < 4; j++) tacc[j] = make_float4(0.f, 0.f, 0.f, 0.f);

    const size_t rowbase = (size_t)b * N_ + (size_t)chunk * NPB + (size_t)wave * NPW;

    for (int step = 0; step < NSTEP; step++) {
        const int r = step * 4 + g;
        const float* rp = means + (rowbase + r) * D_;
        float4 m[4];
        #pragma unroll
        for (int jj = 0; jj < 2; jj++)
            #pragma unroll
            for (int h = 0; h < 2; h++)
                m[jj * 2 + h] = ((const float4*)rp)[q * 2 + 32 * jj + h];
        if (WRITE_H) {
            __half* hp = mh + (rowbase + r) * D_;
            #pragma unroll
            for (int jj = 0; jj < 2; jj++) {
                union { uint4 u4; __half2 h2[4]; } pk;
                pk.h2[0] = __floats2half2_rn(m[jj*2].x,   m[jj*2].y);
                pk.h2[1] = __floats2half2_rn(m[jj*2].z,   m[jj*2].w);
                pk.h2[2] = __floats2half2_rn(m[jj*2+1].x, m[jj*2+1].y);
                pk.h2[3] = __floats2half2_rn(m[jj*2+1].z, m[jj*2+1].w);
                *(uint4*)(hp + q * 8 + 128 * jj) = pk.u4;
            }
        }
        SCORE_AND_UPDATE()
    }

    float Mw = runM;
    Mw = fmaxf(Mw, __shfl_xor(Mw, 16, 64));
    Mw = fmaxf(Mw, __shfl_xor(Mw, 32, 64));
    const float aw = __expf(runM - Mw);
    float Sa = runS * aw;
    Sa += __shfl_xor(Sa, 16, 64);
    Sa += __shfl_xor(Sa, 32, 64);
    #pragma unroll
    for (int j = 0; j < 4; j++) {
        tacc[j].x *= aw; tacc[j].y *= aw; tacc[j].z *= aw; tacc[j].w *= aw;
        tacc[j].x += __shfl_xor(tacc[j].x, 16, 64);
        tacc[j].y += __shfl_xor(tacc[j].y, 16, 64);
        tacc[j].z += __shfl_xor(tacc[j].z, 16, 64);
        tacc[j].w += __shfl_xor(tacc[j].w, 16, 64);
        tacc[j].x += __shfl_xor(tacc[j].x, 32, 64);
        tacc[j].y += __shfl_xor(tacc[j].y, 32, 64);
        tacc[j].z += __shfl_xor(tacc[j].z, 32, 64);
        tacc[j].w += __shfl_xor(tacc[j].w, 32, 64);
    }
    if (lane < 16) {
        #pragma unroll
        for (int j = 0; j < 4; j++)
            ((float4*)shbuf[wave])[q * 2 + 32 * (j >> 1) + (j & 1)] = tacc[j];
    }
    if (lane == 0) { wM[wave] = Mw; wS[wave] = Sa; }
    __syncthreads();
    const float Mb = fmaxf(fmaxf(wM[0], wM[1]), fmaxf(wM[2], wM[3]));
    const float a0 = __expf(wM[0] - Mb), a1 = __expf(wM[1] - Mb),
                a2 = __expf(wM[2] - Mb), a3 = __expf(wM[3] - Mb);
    const float Tc = a0 * shbuf[0][tid] + a1 * shbuf[1][tid] +
                     a2 * shbuf[2][tid] + a3 * shbuf[3][tid];
    Tbuf[((size_t)(b * NCH + chunk)) * D_ + tid] = Tc;
    if (tid == 0)
        stats[b * NCH + chunk] = make_float2(
            Mb, a0 * wS[0] + a1 * wS[1] + a2 * wS[2] + a3 * wS[3]);
}

__global__ __launch_bounds__(256) void fused_f16_kernel(const __half* __restrict__ mh,
                                                        const float* __restrict__ v,
                                                        const float* __restrict__ P,
                                                        const int* __restrict__ flag,
                                                        float* __restrict__ Tbuf,
                                                        float2* __restrict__ stats) {
    const int b = blockIdx.y, chunk = blockIdx.x;
    const int tid = threadIdx.x, wave = tid >> 6, lane = tid & 63;
    const int q = lane & 15, g = lane >> 4;
    __shared__ __align__(16) float vsh[D_];
    __shared__ __align__(16) float shbuf[4][D_];
    __shared__ __align__(16) float srows[4][4][D_];
    __shared__ float wM[4], wS[4];
    vsh[tid] = v[b * D_ + tid];
    __syncthreads();
    float4 vr[4];
    #pragma unroll
    for (int jj = 0; jj < 2; jj++)
        #pragma unroll
        for (int h = 0; h < 2; h++)
            vr[jj * 2 + h] = ((const float4*)vsh)[q * 2 + 32 * jj + h];
    const int flg = *flag;

    float runM = -INFINITY, runS = 0.f;
    float4 tacc[4];
    #pragma unroll
    for (int j = 0; j < 4; j++) tacc[j] = make_float4(0.f, 0.f, 0.f, 0.f);

    const size_t rowbase = (size_t)b * N_ + (size_t)chunk * NPB + (size_t)wave * NPW;

    for (int step = 0; step < NSTEP; step++) {
        const int r = step * 4 + g;
        const __half* rp = mh + (rowbase + r) * D_;
        float4 m[4];
        #pragma unroll
        for (int jj = 0; jj < 2; jj++) {
            float4 raw = ((const float4*)rp)[q + 16 * jj];
            const __half2* hp2 = (const __half2*)&raw;
            const float2 f0 = __half22float2(hp2[0]);
            const float2 f1 = __half22float2(hp2[1]);
            const float2 f2 = __half22float2(hp2[2]);
            const float2 f3 = __half22float2(hp2[3]);
            m[jj * 2 + 0] = make_float4(f0.x, f0.y, f1.x, f1.y);
            m[jj * 2 + 1] = make_float4(f2.x, f2.y, f3.x, f3.y);
        }
        SCORE_AND_UPDATE()
    }

    float Mw = runM;
    Mw = fmaxf(Mw, __shfl_xor(Mw, 16, 64));
    Mw = fmaxf(Mw, __shfl_xor(Mw, 32, 64));
    const float aw = __expf(runM - Mw);
    float Sa = runS * aw;
    Sa += __shfl_xor(Sa, 16, 64);
    Sa += __shfl_xor(Sa, 32, 64);
    #pragma unroll
    for (int j = 0; j < 4; j++) {
        tacc[j].x *= aw; tacc[j].y *= aw; tacc[j].z *= aw; tacc[j].w *= aw;
        tacc[j].x += __shfl_xor(tacc[j].x, 16, 64);
        tacc[j].y += __shfl_xor(tacc[j].y, 16, 64);
        tacc[j].z += __shfl_xor(tacc[j].z, 16, 64);
        tacc[j].w += __shfl_xor(tacc[j].w, 16, 64);
        tacc[j].x += __shfl_xor(tacc[j].x, 32, 64);
        tacc[j].y += __shfl_xor(tacc[j].y, 32, 64);
        tacc[j].z += __shfl_xor(tacc[j].z, 32, 64);
        tacc[j].w += __shfl_xor(tacc[j].w, 32, 64);
    }
    if (lane < 16) {
        #pragma unroll
        for (int j = 0; j < 4; j++)
            ((float4*)shbuf[wave])[q * 2 + 32 * (j >> 1) + (j & 1)] = tacc[j];
    }
    if (lane == 0) { wM[wave] = Mw; wS[wave] = Sa; }
    __syncthreads();
    const float Mb = fmaxf(fmaxf(wM[0], wM[1]), fmaxf(wM[2], wM[3]));
    const float a0 = __expf(wM[0] - Mb), a1 = __expf(wM[1] - Mb),
                a2 = __expf(wM[2] - Mb), a3 = __expf(wM[3] - Mb);
    const float Tc = a0 * shbuf[0][tid] + a1 * shbuf[1][tid] +
                     a2 * shbuf[2][tid] + a3 * shbuf[3][tid];
    Tbuf[((size_t)(b * NCH + chunk)) * D_ + tid] = Tc;
    if (tid == 0)
        stats[b * NCH + chunk] = make_float2(
            Mb, a0 * wS[0] + a1 * wS[1] + a2 * wS[2] + a3 * wS[3]);
}

__global__ __launch_bounds__(256) void combine_kernel(const float* __restrict__ Tbuf,
                                                      const float2* __restrict__ stats,
                                                      const float* __restrict__ P,
                                                      const int* __restrict__ flag,
                                                      float* __restrict__ v,
                                                      float* __restrict__ out) {
    const int b = blockIdx.x, d = threadIdx.x;
    __shared__ float Msh[NCH], Ssh[NCH];
    __shared__ float zsh[D_];
    if (d < NCH) {
        const float2 st = stats[b * NCH + d];
        Msh[d] = st.x; Ssh[d] = st.y;
    }
    __syncthreads();
    float M = -INFINITY;
    for (int c = 0; c < NCH; c++) M = fmaxf(M, Msh[c]);
    float S = 0.f, acc = 0.f;
    for (int c = 0; c < NCH; c++) {
        const float a = __expf(Msh[c] - M);
        S += a * Ssh[c];
        acc += a * Tbuf[((size_t)(b * NCH + c)) * D_ + d];
    }
    const float z = acc / S;
    if (out) out[b * D_ + d] = z;
    if (*flag == 0) {
        v[b * D_ + d] = 2.0f * z;
        return;
    }
    zsh[d] = z;
    __syncthreads();
    float vv = 0.f;
    for (int e = 0; e < D_; e++)
        vv += (P[d * D_ + e] + P[e * D_ + d]) * zsh[e];
    v[b * D_ + d] = vv;
}

extern "C" void kernel_launch(void* const* d_in, const int* in_sizes, int n_in,
                              void* d_out, int out_size, void* d_ws, size_t ws_size,
                              hipStream_t stream) {
    // inputs: 0=x (unused), 1=z, 2=means, 3=precision, 4=iterations(=10)
    const float* z0    = (const float*)d_in[1];
    const float* means = (const float*)d_in[2];
    const float* P     = (const float*)d_in[3];
    float* out = (float*)d_out;

    char* ws = (char*)d_ws;
    size_t off = 0;
    int*    flag  = (int*)ws;                     off = 256;
    float*  v     = (float*)(ws + off);           off += (size_t)B_ * D_ * 4;
    float*  Tbuf  = (float*)(ws + off);           off += (size_t)B_ * NCH * D_ * 4;
    float2* stats = (float2*)(ws + off);          off += (size_t)B_ * NCH * 8;
    off = (off + 255) & ~(size_t)255;
    float*  pT    = (float*)(ws + off);           off += 2ull * 1024 * D_ * 4;
    float2* pS    = (float2*)(ws + off);          off += 2ull * 1024 * 8;
    off = (off + 255) & ~(size_t)255;
    float*  Cn    = (float*)(ws + off);           off += (size_t)B_ * N_ * 4;
    off = (off + 255) & ~(size_t)255;
    __half* mh    = (__half*)(ws + off);
    const size_t coop_need  = off;                               // ~7.4 MiB
    const size_t full_need  = off + (size_t)B_ * N_ * D_ * 2;    // + 128 MiB
    const bool use_h = (ws_size >= full_need);
    const bool ws_ok = (ws_size >= coop_need);

    flag_kernel<<<dim3(1), dim3(256), 0, stream>>>(P, flag);

    // ---- cooperative persistent path (preferred) ----
    if (ws_ok) {
        // Cn precompute (no-op when P == I)
        cn_kernel<<<dim3(B_ * N_ / CNR), dim3(256), 0, stream>>>(means, P, flag, Cn);

        void* args[] = {(void*)&means, (void*)&z0, (void*)&P, (void*)&flag,
                        (void*)&Cn, (void*)&mh, (void*)&pT, (void*)&pS, (void*)&out};
        int nb = 0;
        if (use_h) {
            if (hipOccupancyMaxActiveBlocksPerMultiprocessor(
                    &nb, persistent_kernel<true, 16>, 256, 0) == hipSuccess && nb >= 4) {
                if (hipLaunchCooperativeKernel(persistent_kernel<true, 16>,
                        dim3(1024), dim3(256), args, 0, stream) == hipSuccess)
                    return;
            }
            nb = 0;
            if (hipOccupancyMaxActiveBlocksPerMultiprocessor(
                    &nb, persistent_kernel<true, 8>, 256, 0) == hipSuccess && nb >= 2) {
                if (hipLaunchCooperativeKernel(persistent_kernel<true, 8>,
                        dim3(512), dim3(256), args, 0, stream) == hipSuccess)
                    return;
            }
        } else {
            if (hipOccupancyMaxActiveBlocksPerMultiprocessor(
                    &nb, persistent_kernel<false, 16>, 256, 0) == hipSuccess && nb >= 4) {
                if (hipLaunchCooperativeKernel(persistent_kernel<false, 16>,
                        dim3(1024), dim3(256), args, 0, stream) == hipSuccess)
                    return;
            }
            nb = 0;
            if (hipOccupancyMaxActiveBlocksPerMultiprocessor(
                    &nb, persistent_kernel<false, 8>, 256, 0) == hipSuccess && nb >= 2) {
                if (hipLaunchCooperativeKernel(persistent_kernel<false, 8>,
                        dim3(512), dim3(256), args, 0, stream) == hipSuccess)
                    return;
            }
        }
    }

    // ---- fallback multi-kernel path (round-4) ----
    vcalc_kernel<<<dim3(B_), dim3(256), 0, stream>>>(P, z0, flag, v);
    if (use_h) {
        fused_f32_kernel<true><<<dim3(NCH, B_), dim3(256), 0, stream>>>(
            means, v, P, flag, mh, Tbuf, stats);
        combine_kernel<<<dim3(B_), dim3(256), 0, stream>>>(Tbuf, stats, P, flag, v, nullptr);
        for (int t = 1; t < 10; t++) {
            fused_f16_kernel<<<dim3(NCH, B_), dim3(256), 0, stream>>>(
                mh, v, P, flag, Tbuf, stats);
            combine_kernel<<<dim3(B_), dim3(256), 0, stream>>>(Tbuf, stats, P, flag, v,
                                                               (t == 9) ? out : nullptr);
        }
    } else {
        for (int t = 0; t < 10; t++) {
            fused_f32_kernel<false><<<dim3(NCH, B_), dim3(256), 0, stream>>>(
                means, v, P, flag, nullptr, Tbuf, stats);
            combine_kernel<<<dim3(B_), dim3(256), 0, stream>>>(Tbuf, stats, P, flag, v,
                                                               (t == 9) ? out : nullptr);
        }
    }
}